// Round 1
// baseline (2970.072 us; speedup 1.0000x reference)
//
#include <hip/hip_runtime.h>

// ============================================================================
// SignLLM forward, fp32. B=4, T=32 -> nc=16 clips (frames 0,2,..,30), D=512.
// All convs have input T=1 => only the kt=1 temporal slice of each 3D kernel
// contributes. BN is training-mode with per-clip-batch stats (16 groups).
// Output: d_out[0..31] = widx (4,8) as float, d_out[32] = total loss.
// ============================================================================

// ---- workspace layout (float offsets). Peak ~13.64M floats = 54.6 MB ----
static const size_t OFF_X1P   = 0;          // (64,64,32,32)  = 4,194,304
static const size_t OFF_X2P   = 0;          // (64,128,16,16) = 2,097,152 (x1p dead)
static const size_t OFF_Y2    = 4194304;    // (64,128,32,32) = 8,388,608
static const size_t OFF_Y3    = 4194304;    // (64,256,16,16) = 4,194,304 (y2 dead)
static const size_t OFF_SC    = 12582912;   // 4096
static const size_t OFF_SH    = 12587008;   // 4096
static const size_t OFF_X3P   = 12591104;   // (64,256,4,4) = 262,144
static const size_t OFF_Y4    = 12853248;   // 262,144
static const size_t OFF_X4    = 13115392;   // 262,144
static const size_t OFF_FEAT  = 13377536;   // (64,512) = 32,768
static const size_t OFF_QUANT = 13410304;   // 32,768
static const size_t OFF_GI    = 13443072;   // (60,1536) = 92,160
static const size_t OFF_H1    = 13535232;   // (60,512) = 30,720
static const size_t OFF_H2    = 13565952;   // 30,720
static const size_t OFF_WEMB  = 13596672;   // (32,512) = 16,384
static const size_t OFF_HH1   = 13613056;   // 2,048
static const size_t OFF_HH2   = 13615104;   // 4,096
static const size_t OFF_LOGIT = 13619200;   // 12,000
static const size_t OFF_ACC   = 13631200;   // [0]=commit_sum [1]=ctx_sum [2]=align_sum

__global__ void k_zero(float* acc) {
    if (threadIdx.x < 8) acc[threadIdx.x] = 0.f;
}

// ---- conv1 at one output position (ic=3, middle temporal slice) ----
__device__ __forceinline__ float conv1_at(const float* __restrict__ vb,
                                          const float* __restrict__ wsm,
                                          float bias, int h, int w) {
    float a = bias;
#pragma unroll
    for (int ic = 0; ic < 3; ++ic) {
        const float* vp = vb + (size_t)ic * 131072;  // 32*64*64
#pragma unroll
        for (int r = 0; r < 3; ++r) {
            int hh = h + r - 1;
            if (hh < 0 || hh > 63) continue;
#pragma unroll
            for (int q = 0; q < 3; ++q) {
                int ww = w + q - 1;
                if (ww < 0 || ww > 63) continue;
                a += vp[hh * 64 + ww] * wsm[ic * 9 + r * 3 + q];
            }
        }
    }
    return a;
}

// BN1 stats by recomputing conv1 (cheap: 27 MAC/elem) -> scale/shift per (c,oc)
__global__ void k_conv1_stats(const float* __restrict__ videos, const float* __restrict__ w1,
                              const float* __restrict__ b1, const float* __restrict__ g1,
                              const float* __restrict__ be1, float* __restrict__ scale,
                              float* __restrict__ shift) {
    int c = blockIdx.x, oc = blockIdx.y, tid = threadIdx.x;
    __shared__ float wsm[27];
    if (tid < 27) {
        int ic = tid / 9, k = tid % 9;
        wsm[tid] = w1[((size_t)(oc * 3 + ic) * 3 + 1) * 9 + k];
    }
    __syncthreads();
    float bias = b1[oc];
    float s = 0.f, s2 = 0.f;
    for (int p = tid; p < 16384; p += 256) {
        int b = p >> 12, rem = p & 4095;
        int h = rem >> 6, w = rem & 63;
        const float* vb = videos + ((size_t)b * 96 + 2 * c) * 4096;  // b*3*32 + 2c
        float a = conv1_at(vb, wsm, bias, h, w);
        s += a; s2 += a * a;
    }
    __shared__ float rs[256], rq[256];
    rs[tid] = s; rq[tid] = s2; __syncthreads();
    for (int k = 128; k > 0; k >>= 1) {
        if (tid < k) { rs[tid] += rs[tid + k]; rq[tid] += rq[tid + k]; }
        __syncthreads();
    }
    if (tid == 0) {
        float m = rs[0] * (1.f / 16384.f);
        float var = rq[0] * (1.f / 16384.f) - m * m;
        float sc = g1[oc] * rsqrtf(var + 1e-5f);
        scale[c * 64 + oc] = sc;
        shift[c * 64 + oc] = be1[oc] - m * sc;
    }
}

// conv1 + BN + relu + 2x2 maxpool -> x1p (64,64,32,32)
__global__ void k_conv1_apply(const float* __restrict__ videos, const float* __restrict__ w1,
                              const float* __restrict__ b1, const float* __restrict__ scale,
                              const float* __restrict__ shift, float* __restrict__ x1p) {
    size_t idx = (size_t)blockIdx.x * 256 + threadIdx.x;  // 4,194,304
    int ow = (int)(idx & 31), oh = (int)(idx >> 5) & 31;
    int oc = (int)(idx >> 10) & 63, n = (int)(idx >> 16);
    int c = n >> 2, b = n & 3;
    __shared__ float wsm[27];
    if (threadIdx.x < 27) {
        int ic = threadIdx.x / 9, k = threadIdx.x % 9;
        wsm[threadIdx.x] = w1[((size_t)(oc * 3 + ic) * 3 + 1) * 9 + k];
    }
    __syncthreads();
    float sc = scale[c * 64 + oc], sh = shift[c * 64 + oc];
    float bias = b1[oc];
    const float* vb = videos + ((size_t)b * 96 + 2 * c) * 4096;
    float m = 0.f;  // relu floor
#pragma unroll
    for (int dh = 0; dh < 2; ++dh)
#pragma unroll
        for (int dw = 0; dw < 2; ++dw) {
            float a = conv1_at(vb, wsm, bias, 2 * oh + dh, 2 * ow + dw);
            m = fmaxf(m, a * sc + sh);
        }
    x1p[idx] = m;
}

// Direct 3x3 conv (middle temporal slice), 16 oc per block in registers.
template <int IC, int H, int W>
__global__ void k_conv3x3(const float* __restrict__ in, const float* __restrict__ wt,
                          const float* __restrict__ bias, float* __restrict__ out, int OC) {
    constexpr int ROWS = 256 / W;
    int tid = threadIdx.x;
    int w = tid % W, h0 = tid / W;
    int h = blockIdx.x * ROWS + h0;
    int oc0 = blockIdx.y * 16;
    int n = blockIdx.z;
    float acc[16];
#pragma unroll
    for (int j = 0; j < 16; ++j) acc[j] = 0.f;
    const float* inN = in + (size_t)n * IC * H * W;
    for (int ic = 0; ic < IC; ++ic) {
        const float* p = inN + (size_t)ic * H * W;
        float v[9];
#pragma unroll
        for (int r = 0; r < 3; ++r) {
            int hh = h + r - 1;
#pragma unroll
            for (int s = 0; s < 3; ++s) {
                int ww = w + s - 1;
                v[r * 3 + s] = (hh >= 0 && hh < H && ww >= 0 && ww < W) ? p[hh * W + ww] : 0.f;
            }
        }
        const float* wp = wt + ((size_t)oc0 * IC + ic) * 27 + 9;
#pragma unroll
        for (int j = 0; j < 16; ++j) {
            const float* wj = wp + (size_t)j * IC * 27;
            float a = acc[j];
#pragma unroll
            for (int k = 0; k < 9; ++k) a += v[k] * wj[k];
            acc[j] = a;
        }
    }
#pragma unroll
    for (int j = 0; j < 16; ++j)
        out[(((size_t)n * OC + oc0 + j) * H + h) * W + w] = acc[j] + bias[oc0 + j];
}

// generic per-(clip,channel) BN stats -> scale/shift
__global__ void k_bn_stats(const float* __restrict__ buf, const float* __restrict__ g,
                           const float* __restrict__ be, float* __restrict__ scale,
                           float* __restrict__ shift, int C, int HW) {
    int c = blockIdx.x, ch = blockIdx.y, tid = threadIdx.x;
    float s = 0.f, s2 = 0.f;
    for (int b = 0; b < 4; ++b) {
        const float* p = buf + ((size_t)(c * 4 + b) * C + ch) * HW;
        for (int i = tid; i < HW; i += 256) { float v = p[i]; s += v; s2 += v * v; }
    }
    __shared__ float rs[256], rq[256];
    rs[tid] = s; rq[tid] = s2; __syncthreads();
    for (int k = 128; k > 0; k >>= 1) {
        if (tid < k) { rs[tid] += rs[tid + k]; rq[tid] += rq[tid + k]; }
        __syncthreads();
    }
    if (tid == 0) {
        float inv = 1.f / (float)(4 * HW);
        float m = rs[0] * inv, var = rq[0] * inv - m * m;
        float sc = g[ch] * rsqrtf(var + 1e-5f);
        scale[c * C + ch] = sc;
        shift[c * C + ch] = be[ch] - m * sc;
    }
}

// BN + relu + 2x2 maxpool
__global__ void k_bn_apply_pool(const float* __restrict__ in, const float* __restrict__ scale,
                                const float* __restrict__ shift, float* __restrict__ out,
                                int C, int H, int W) {
    int OH = H >> 1, OW = W >> 1;
    size_t idx = (size_t)blockIdx.x * 256 + threadIdx.x;
    int ow = (int)(idx % OW);
    size_t r = idx / OW;
    int oh = (int)(r % OH); r /= OH;
    int ch = (int)(r % C);
    int n = (int)(r / C);
    int c = n >> 2;
    float sc = scale[c * C + ch], sh = shift[c * C + ch];
    const float* p = in + (((size_t)n * C + ch) * H + 2 * oh) * W + 2 * ow;
    float m = 0.f;
    m = fmaxf(m, p[0] * sc + sh);
    m = fmaxf(m, p[1] * sc + sh);
    m = fmaxf(m, p[W] * sc + sh);
    m = fmaxf(m, p[W + 1] * sc + sh);
    out[idx] = m;
}

// BN + relu + 4x4 avgpool (16x16 -> 4x4)
__global__ void k_bn_apply_avgpool4(const float* __restrict__ in, const float* __restrict__ scale,
                                    const float* __restrict__ shift, float* __restrict__ out) {
    size_t idx = (size_t)blockIdx.x * 256 + threadIdx.x;  // 262,144
    int j = (int)(idx & 3), i = (int)(idx >> 2) & 3;
    int ch = (int)(idx >> 4) & 255, n = (int)(idx >> 12);
    int c = n >> 2;
    float sc = scale[c * 256 + ch], sh = shift[c * 256 + ch];
    const float* p = in + (((size_t)n * 256 + ch) * 16 + i * 4) * 16 + j * 4;
    float s = 0.f;
#pragma unroll
    for (int r = 0; r < 4; ++r)
#pragma unroll
        for (int q = 0; q < 4; ++q) s += fmaxf(p[r * 16 + q] * sc + sh, 0.f);
    out[idx] = s * (1.f / 16.f);
}

// temporal conv collapses to 1x1: y4[n][o][p] = b[o] + sum_i x3p[n][i][p]*w[o][i][kt=1]
__global__ void k_tconv(const float* __restrict__ x3p, const float* __restrict__ tw,
                        const float* __restrict__ tb, float* __restrict__ y4) {
    size_t idx = (size_t)blockIdx.x * 256 + threadIdx.x;  // 262,144
    int p = (int)(idx & 15), o = (int)(idx >> 4) & 255, n = (int)(idx >> 12);
    const float* xr = x3p + (size_t)n * 4096 + p;
    float a = tb[o];
    for (int i = 0; i < 256; ++i) a += xr[i * 16] * tw[((size_t)o * 256 + i) * 3 + 1];
    y4[idx] = a;
}

__global__ void k_bn_apply(const float* __restrict__ in, const float* __restrict__ scale,
                           const float* __restrict__ shift, float* __restrict__ out) {
    size_t idx = (size_t)blockIdx.x * 256 + threadIdx.x;  // 262,144
    int ch = (int)(idx >> 4) & 255, n = (int)(idx >> 12);
    int c = n >> 2;
    float sc = scale[c * 256 + ch], sh = shift[c * 256 + ch];
    out[idx] = fmaxf(in[idx] * sc + sh, 0.f);
}

// features[ro=b*16+c][d] = x4row(n=c*4+b) . proj_w[d] + proj_b[d]
// grid 64 blocks = col-chunks of 8; thread: row = tid>>2, col pair = tid&3
__global__ void k_proj(const float* __restrict__ x4, const float* __restrict__ pw,
                       const float* __restrict__ pb, float* __restrict__ feat) {
    int d0 = blockIdx.x * 8;
    int ro = threadIdx.x >> 2;
    int cp = threadIdx.x & 3;
    int c0 = d0 + cp * 2, c1 = c0 + 1;
    int n = (ro & 15) * 4 + (ro >> 4);
    const float* x = x4 + (size_t)n * 4096;
    const float* w0 = pw + (size_t)c0 * 4096;
    const float* w1 = pw + (size_t)c1 * 4096;
    float a0 = pb[c0], a1 = pb[c1];
    for (int k = 0; k < 4096; ++k) { float f = x[k]; a0 += f * w0[k]; a1 += f * w1[k]; }
    feat[(size_t)ro * 512 + c0] = a0;
    feat[(size_t)ro * 512 + c1] = a1;
}

// VQ: argmin over 1024 codes (first-min tie-break), copy code, accumulate min-dist
__global__ void k_vq(const float* __restrict__ feat, const float* __restrict__ cb,
                     float* __restrict__ quant, float* __restrict__ acc) {
    int row = blockIdx.x, tid = threadIdx.x;
    __shared__ float f[512];
    for (int k = tid; k < 512; k += 256) f[k] = feat[(size_t)row * 512 + k];
    __syncthreads();
    float best = 3.4e38f; int bidx = 0;
    for (int j = tid; j < 1024; j += 256) {
        const float* c = cb + (size_t)j * 512;
        float d2 = 0.f;
        for (int k = 0; k < 512; ++k) { float t = f[k] - c[k]; d2 += t * t; }
        if (d2 < best) { best = d2; bidx = j; }
    }
    __shared__ float rd[256]; __shared__ int ri[256];
    rd[tid] = best; ri[tid] = bidx; __syncthreads();
    for (int k = 128; k > 0; k >>= 1) {
        if (tid < k) {
            float od = rd[tid + k]; int oi = ri[tid + k];
            if (od < rd[tid] || (od == rd[tid] && oi < ri[tid])) { rd[tid] = od; ri[tid] = oi; }
        }
        __syncthreads();
    }
    __shared__ int wsel;
    if (tid == 0) { wsel = ri[0]; atomicAdd(acc, rd[0]); }
    __syncthreads();
    const float* c = cb + (size_t)wsel * 512;
    for (int k = tid; k < 512; k += 256) quant[(size_t)row * 512 + k] = c[k];
}

// gi = X @ w_ih.T + b_ih for rows (b,t), t in 0..14. xs = row stride of X (16 or 15)
__global__ void k_gru_gi(const float* __restrict__ x, int xs, const float* __restrict__ wih,
                         const float* __restrict__ bih, float* __restrict__ gi) {
    int r = blockIdx.x;  // 0..59
    int b = r / 15, t = r % 15;
    const float* xr = x + ((size_t)(b * xs + t)) * 512;
    __shared__ float xsRow[512];
    for (int k = threadIdx.x; k < 512; k += 256) xsRow[k] = xr[k];
    __syncthreads();
    for (int d = threadIdx.x; d < 1536; d += 256) {
        const float* wr = wih + (size_t)d * 512;
        float a = bih[d];
        for (int k = 0; k < 512; ++k) a += xsRow[k] * wr[k];
        gi[(size_t)r * 1536 + d] = a;
    }
}

// One GRU time step. 16 blocks = (b, d-quadrant); 384 threads = (gate, d_local).
__global__ void k_gru_step(const float* __restrict__ gi, const float* __restrict__ whh,
                           const float* __restrict__ bhh, float* __restrict__ hseq, int t) {
    int blk = blockIdx.x;
    int b = blk >> 2, dq = blk & 3;
    int tid = threadIdx.x;  // 0..383
    __shared__ float hprev[512];
    __shared__ float gd[3][128];
    for (int k = tid; k < 512; k += 384)
        hprev[k] = (t == 0) ? 0.f : hseq[((size_t)(b * 15 + t - 1)) * 512 + k];
    __syncthreads();
    int gate = tid / 128, dl = tid % 128;
    int d = dq * 128 + dl;
    {
        const float* wr = whh + (size_t)(gate * 512 + d) * 512;
        float a = 0.f;
        for (int k = 0; k < 512; ++k) a += hprev[k] * wr[k];
        gd[gate][dl] = a + bhh[gate * 512 + d];
    }
    __syncthreads();
    if (tid < 128) {
        int dd = dq * 128 + tid;
        const float* gir = gi + (size_t)(b * 15 + t) * 1536;
        float rr = 1.f / (1.f + expf(-(gir[dd] + gd[0][tid])));
        float zz = 1.f / (1.f + expf(-(gir[512 + dd] + gd[1][tid])));
        float nn = tanhf(gir[1024 + dd] + rr * gd[2][tid]);
        hseq[((size_t)(b * 15 + t)) * 512 + dd] = (1.f - zz) * nn + zz * hprev[dd];
    }
}

__global__ void k_ctx_loss(const float* __restrict__ h2, const float* __restrict__ feat,
                           float* __restrict__ acc) {
    int tid = threadIdx.x;
    size_t idx = (size_t)blockIdx.x * 256 + tid;  // 30720 total
    int d = (int)(idx & 511);
    int rt = (int)(idx >> 9);
    int t = rt % 15, b = rt / 15;
    float diff = h2[idx] - feat[((size_t)(b * 16 + t + 1)) * 512 + d];
    float v = diff * diff;
    __shared__ float rs[256];
    rs[tid] = v; __syncthreads();
    for (int k = 128; k > 0; k >>= 1) { if (tid < k) rs[tid] += rs[tid + k]; __syncthreads(); }
    if (tid == 0) atomicAdd(acc + 1, rs[0]);
}

// word VQ: mean of char pair -> nearest of 256 word codes; widx -> d_out (as float)
__global__ void k_word_vq(const float* __restrict__ quant, const float* __restrict__ wcb,
                          float* __restrict__ wemb, float* __restrict__ out_widx) {
    int row = blockIdx.x;  // 0..31 = b*8+wi
    int b = row >> 3, wi = row & 7;
    int tid = threadIdx.x;
    __shared__ float f[512];
    for (int k = tid; k < 512; k += 256)
        f[k] = 0.5f * (quant[((size_t)(b * 16 + 2 * wi)) * 512 + k] +
                       quant[((size_t)(b * 16 + 2 * wi + 1)) * 512 + k]);
    __syncthreads();
    const float* cp = wcb + (size_t)tid * 512;
    float d2 = 0.f;
    for (int k = 0; k < 512; ++k) { float t = f[k] - cp[k]; d2 += t * t; }
    __shared__ float rd[256]; __shared__ int ri[256];
    rd[tid] = d2; ri[tid] = tid; __syncthreads();
    for (int k = 128; k > 0; k >>= 1) {
        if (tid < k) {
            float od = rd[tid + k]; int oi = ri[tid + k];
            if (od < rd[tid] || (od == rd[tid] && oi < ri[tid])) { rd[tid] = od; ri[tid] = oi; }
        }
        __syncthreads();
    }
    __shared__ int wsel;
    if (tid == 0) { wsel = ri[0]; out_widx[row] = (float)ri[0]; }
    __syncthreads();
    const float* cb = wcb + (size_t)wsel * 512;
    for (int k = tid; k < 512; k += 256) wemb[(size_t)row * 512 + k] = cb[k];
}

__global__ void k_align(const float* __restrict__ wemb, const float* __restrict__ aw,
                        const float* __restrict__ ab, float* __restrict__ acc) {
    int row = blockIdx.x, tid = threadIdx.x;
    __shared__ float e[512];
    for (int k = tid; k < 512; k += 256) e[k] = wemb[(size_t)row * 512 + k];
    __syncthreads();
    float local = 0.f;
    for (int d = tid; d < 512; d += 256) {
        const float* wr = aw + (size_t)d * 512;
        float a = ab[d] - e[d];
        for (int k = 0; k < 512; ++k) a += e[k] * wr[k];
        local += a * a;
    }
    __shared__ float rs[256];
    rs[tid] = local; __syncthreads();
    for (int k = 128; k > 0; k >>= 1) { if (tid < k) rs[tid] += rs[tid + k]; __syncthreads(); }
    if (tid == 0) atomicAdd(acc + 2, rs[0]);
}

__global__ void k_ctx_dec1(const float* __restrict__ wemb, const float* __restrict__ w,
                           const float* __restrict__ bb, float* __restrict__ hh1) {
    int b = blockIdx.x, tid = threadIdx.x;
    __shared__ float cx[512];
    for (int d = tid; d < 512; d += 256) {
        float s = 0.f;
#pragma unroll
        for (int wi = 0; wi < 8; ++wi) s += wemb[((size_t)(b * 8 + wi)) * 512 + d];
        cx[d] = s * 0.125f;
    }
    __syncthreads();
    for (int d = tid; d < 512; d += 256) {
        const float* wr = w + (size_t)d * 512;
        float a = bb[d];
        for (int k = 0; k < 512; ++k) a += cx[k] * wr[k];
        hh1[(size_t)b * 512 + d] = fmaxf(a, 0.f);
    }
}

__global__ void k_dec2(const float* __restrict__ hh1, const float* __restrict__ w,
                       const float* __restrict__ bb, float* __restrict__ hh2) {
    int b = blockIdx.x, tid = threadIdx.x;
    __shared__ float x[512];
    for (int k = tid; k < 512; k += 256) x[k] = hh1[(size_t)b * 512 + k];
    __syncthreads();
    for (int d = tid; d < 1024; d += 256) {
        const float* wr = w + (size_t)d * 512;
        float a = bb[d];
        for (int k = 0; k < 512; ++k) a += x[k] * wr[k];
        hh2[(size_t)b * 1024 + d] = fmaxf(a, 0.f);
    }
}

__global__ void k_dec3(const float* __restrict__ hh2, const float* __restrict__ w,
                       const float* __restrict__ bb, float* __restrict__ logits) {
    int b = blockIdx.x, tid = threadIdx.x;
    __shared__ float x[1024];
    for (int k = tid; k < 1024; k += 256) x[k] = hh2[(size_t)b * 1024 + k];
    __syncthreads();
    for (int d = tid; d < 3000; d += 256) {
        const float* wr = w + (size_t)d * 1024;
        float a = bb[d];
        for (int k = 0; k < 1024; ++k) a += x[k] * wr[k];
        logits[(size_t)b * 3000 + d] = a;
    }
}

// log-softmax CE (sum over batch of first-token NLL) + combine all loss terms
__global__ void k_final(const float* __restrict__ logits, const int* __restrict__ tokens,
                        const float* __restrict__ acc, float* __restrict__ out_total) {
    int tid = threadIdx.x;
    __shared__ float rs[256];
    __shared__ float sM;
    float tr = 0.f;
    for (int b = 0; b < 4; ++b) {
        const float* lg = logits + (size_t)b * 3000;
        float m = -1e30f;
        for (int d = tid; d < 3000; d += 256) m = fmaxf(m, lg[d]);
        rs[tid] = m; __syncthreads();
        for (int k = 128; k > 0; k >>= 1) { if (tid < k) rs[tid] = fmaxf(rs[tid], rs[tid + k]); __syncthreads(); }
        if (tid == 0) sM = rs[0];
        __syncthreads();
        float M = sM;
        float s = 0.f;
        for (int d = tid; d < 3000; d += 256) s += expf(lg[d] - M);
        rs[tid] = s; __syncthreads();
        for (int k = 128; k > 0; k >>= 1) { if (tid < k) rs[tid] += rs[tid + k]; __syncthreads(); }
        if (tid == 0) {
            int t0 = tokens[b * 10];
            tr += -(lg[t0] - M - logf(rs[0]));
        }
        __syncthreads();
    }
    if (tid == 0) {
        // vq_loss = commit + 0.25*codebook(==commit) + 0.1*ctx; + 0.1*align + translation
        float total = 1.25f * acc[0] * (1.f / 32768.f)
                    + 0.1f  * acc[1] * (1.f / 30720.f)
                    + 0.1f  * acc[2] * (1.f / 16384.f)
                    + tr;
        *out_total = total;
    }
}

extern "C" void kernel_launch(void* const* d_in, const int* in_sizes, int n_in,
                              void* d_out, int out_size, void* d_ws, size_t ws_size,
                              hipStream_t stream) {
    (void)in_sizes; (void)n_in; (void)out_size; (void)ws_size;
    const float* videos   = (const float*)d_in[0];
    const float* conv1_w  = (const float*)d_in[1];
    const float* conv1_b  = (const float*)d_in[2];
    const float* bn1_g    = (const float*)d_in[3];
    const float* bn1_b    = (const float*)d_in[4];
    const float* conv2_w  = (const float*)d_in[5];
    const float* conv2_b  = (const float*)d_in[6];
    const float* bn2_g    = (const float*)d_in[7];
    const float* bn2_b    = (const float*)d_in[8];
    const float* conv3_w  = (const float*)d_in[9];
    const float* conv3_b  = (const float*)d_in[10];
    const float* bn3_g    = (const float*)d_in[11];
    const float* bn3_b    = (const float*)d_in[12];
    const float* tconv_w  = (const float*)d_in[13];
    const float* tconv_b  = (const float*)d_in[14];
    const float* bn4_g    = (const float*)d_in[15];
    const float* bn4_b    = (const float*)d_in[16];
    const float* proj_w   = (const float*)d_in[17];
    const float* proj_b   = (const float*)d_in[18];
    const float* codebook = (const float*)d_in[19];
    const float* word_cb  = (const float*)d_in[20];
    const float* align_w  = (const float*)d_in[21];
    const float* align_b  = (const float*)d_in[22];
    const float* gru_wih0 = (const float*)d_in[23];
    const float* gru_whh0 = (const float*)d_in[24];
    const float* gru_bih0 = (const float*)d_in[25];
    const float* gru_bhh0 = (const float*)d_in[26];
    const float* gru_wih1 = (const float*)d_in[27];
    const float* gru_whh1 = (const float*)d_in[28];
    const float* gru_bih1 = (const float*)d_in[29];
    const float* gru_bhh1 = (const float*)d_in[30];
    const float* dec1_w   = (const float*)d_in[31];
    const float* dec1_b   = (const float*)d_in[32];
    const float* dec2_w   = (const float*)d_in[33];
    const float* dec2_b   = (const float*)d_in[34];
    const float* dec3_w   = (const float*)d_in[35];
    const float* dec3_b   = (const float*)d_in[36];
    const int*   tokens   = (const int*)d_in[37];

    float* wsf  = (float*)d_ws;
    float* out  = (float*)d_out;
    float* x1p  = wsf + OFF_X1P;
    float* x2p  = wsf + OFF_X2P;
    float* y2   = wsf + OFF_Y2;
    float* y3   = wsf + OFF_Y3;
    float* sc   = wsf + OFF_SC;
    float* sh   = wsf + OFF_SH;
    float* x3p  = wsf + OFF_X3P;
    float* y4   = wsf + OFF_Y4;
    float* x4   = wsf + OFF_X4;
    float* feat = wsf + OFF_FEAT;
    float* quant= wsf + OFF_QUANT;
    float* gi   = wsf + OFF_GI;
    float* h1   = wsf + OFF_H1;
    float* h2   = wsf + OFF_H2;
    float* wemb = wsf + OFF_WEMB;
    float* hh1  = wsf + OFF_HH1;
    float* hh2  = wsf + OFF_HH2;
    float* logit= wsf + OFF_LOGIT;
    float* accv = wsf + OFF_ACC;

    k_zero<<<1, 64, 0, stream>>>(accv);
    k_conv1_stats<<<dim3(16, 64), 256, 0, stream>>>(videos, conv1_w, conv1_b, bn1_g, bn1_b, sc, sh);
    k_conv1_apply<<<16384, 256, 0, stream>>>(videos, conv1_w, conv1_b, sc, sh, x1p);
    k_conv3x3<64, 32, 32><<<dim3(4, 8, 64), 256, 0, stream>>>(x1p, conv2_w, conv2_b, y2, 128);
    k_bn_stats<<<dim3(16, 128), 256, 0, stream>>>(y2, bn2_g, bn2_b, sc, sh, 128, 1024);
    k_bn_apply_pool<<<8192, 256, 0, stream>>>(y2, sc, sh, x2p, 128, 32, 32);
    k_conv3x3<128, 16, 16><<<dim3(1, 16, 64), 256, 0, stream>>>(x2p, conv3_w, conv3_b, y3, 256);
    k_bn_stats<<<dim3(16, 256), 256, 0, stream>>>(y3, bn3_g, bn3_b, sc, sh, 256, 256);
    k_bn_apply_avgpool4<<<1024, 256, 0, stream>>>(y3, sc, sh, x3p);
    k_tconv<<<1024, 256, 0, stream>>>(x3p, tconv_w, tconv_b, y4);
    k_bn_stats<<<dim3(16, 256), 256, 0, stream>>>(y4, bn4_g, bn4_b, sc, sh, 256, 16);
    k_bn_apply<<<1024, 256, 0, stream>>>(y4, sc, sh, x4);
    k_proj<<<64, 256, 0, stream>>>(x4, proj_w, proj_b, feat);
    k_vq<<<64, 256, 0, stream>>>(feat, codebook, quant, accv);
    k_gru_gi<<<60, 256, 0, stream>>>(quant, 16, gru_wih0, gru_bih0, gi);
    for (int t = 0; t < 15; ++t)
        k_gru_step<<<16, 384, 0, stream>>>(gi, gru_whh0, gru_bhh0, h1, t);
    k_gru_gi<<<60, 256, 0, stream>>>(h1, 15, gru_wih1, gru_bih1, gi);
    for (int t = 0; t < 15; ++t)
        k_gru_step<<<16, 384, 0, stream>>>(gi, gru_whh1, gru_bhh1, h2, t);
    k_ctx_loss<<<120, 256, 0, stream>>>(h2, feat, accv);
    k_word_vq<<<32, 256, 0, stream>>>(quant, word_cb, wemb, out);
    k_align<<<32, 256, 0, stream>>>(wemb, align_w, align_b, accv);
    k_ctx_dec1<<<4, 256, 0, stream>>>(wemb, dec1_w, dec1_b, hh1);
    k_dec2<<<4, 256, 0, stream>>>(hh1, dec2_w, dec2_b, hh2);
    k_dec3<<<4, 256, 0, stream>>>(hh2, dec3_w, dec3_b, logit);
    k_final<<<1, 256, 0, stream>>>(logit, tokens, accv, out + 32);
}

// Round 4
// 1711.617 us; speedup vs baseline: 1.7352x; 1.7352x over previous
//
#include <hip/hip_runtime.h>

// ============================================================================
// SignLLM forward, fp32. B=4, T=32 -> nc=16 clips, D=512.
// Output: d_out[0..31] = widx (4,8) as float, d_out[32] = total loss.
// R3: identical kernels to R2; FIXED workspace layout. Root cause of R1/R2
// failures: sc/sh/accG/accv (and R1's atomic zone) were placed INSIDE y2's
// extent [4194304, 12582912) -> bn2_stats wrote sc/sh into live y2 and conv2
// clobbered the zeroed accumulators. Layout now keeps long-lived buffers
// past y2; small tail lives in x1p's dead range.
// ============================================================================

// ---- workspace layout (float offsets), peak 12,593,160 floats = 50.4 MB ----
static const size_t OFF_X1P  = 0;         // (64,64,32,32)  4,194,304  [dead after conv2]
static const size_t OFF_Y2   = 4194304;   // (64,128,32,32) 8,388,608  -> ends 12,582,912
static const size_t OFF_X2P  = 0;         // (64,128,16,16) 2,097,152  [x1p dead]
static const size_t OFF_Y3   = 4194304;   // (64,256,16,16) 4,194,304  [y2 dead]
// tail block in [2097152, 4194304): x1p dead by the time these are written
static const size_t OFF_X3P  = 2097152;   // 262,144
static const size_t OFF_Y4   = 2359296;   // 262,144
static const size_t OFF_X4   = 2621440;   // 262,144
static const size_t OFF_FEAT = 2883584;   // (64,512) 32,768
static const size_t OFF_QUANT= 2916352;   // 32,768
static const size_t OFF_GI1  = 2949120;   // (64,1536) 98,304 (rows b*16+t)
static const size_t OFF_GI2  = 3047424;   // 98,304
static const size_t OFF_H1   = 3145728;   // (64,512) rows b*16+t
static const size_t OFF_H2   = 3178496;   // 32,768
static const size_t OFF_WEMB = 3211264;   // (32,512) 16,384
static const size_t OFF_CTX  = 3227648;   // 2,048
static const size_t OFF_HH1  = 3229696;   // 2,048
static const size_t OFF_HH2  = 3231744;   // 4,096
static const size_t OFF_LOG  = 3235840;   // 12,000 -> ends 3,247,840
// long-lived block PAST y2's end (12,582,912):
static const size_t OFF_SC   = 12582912;  // 4,096
static const size_t OFF_SH   = 12587008;  // 4,096
static const size_t OFF_ACCG = 12591104;  // 2,048: conv1 stats sums
static const size_t OFF_ACC  = 12593152;  // 8: [0]=commit [1]=ctx [2]=align
static const size_t ZONE_BEG = 12591104;  // zero accG + acc
static const size_t ZONE_LEN = 12593160 - 12591104;

__global__ void k_zero_zone(float* p, int n) {
    int i = blockIdx.x * 256 + threadIdx.x;
    if (i < n) p[i] = 0.f;
}

// ============================================================================
// conv1 (IC=3, 64x64, pad 1, mid temporal slice). Plane in LDS, 6x6 patch in
// regs, 16 oc/block. grid (4 ocg, 64 n), 256 thr; thread = 4x4 positions.
// ============================================================================
__global__ __launch_bounds__(256, 2) void k_conv1_stats2(
        const float* __restrict__ videos, const float* __restrict__ w1,
        const float* __restrict__ b1, float* __restrict__ accG) {
    __shared__ float sP[3 * 66 * 66];
    __shared__ float wsm[3 * 9 * 16];
    int oc0 = blockIdx.x * 16, n = blockIdx.y;
    int c = n >> 2, b = n & 3;
    int tid = threadIdx.x;
    for (int e = tid; e < 3 * 66 * 66; e += 256) {
        int ic = e / 4356, rem = e % 4356;
        int r = rem / 66, col = rem % 66;
        float v = 0.f;
        if (r >= 1 && r <= 64 && col >= 1 && col <= 64)
            v = videos[((size_t)(b * 3 + ic) * 32 + 2 * c) * 4096 + (r - 1) * 64 + (col - 1)];
        sP[e] = v;
    }
    for (int e = tid; e < 432; e += 256) {
        int ic = e / 144, rem = e % 144, k = rem / 16, j = rem % 16;
        wsm[e] = w1[((size_t)((oc0 + j) * 3 + ic) * 3 + 1) * 9 + k];
    }
    __syncthreads();
    int ph0 = (tid >> 4) * 4, pw0 = (tid & 15) * 4;
    int lane = tid & 63;
    for (int cc = 0; cc < 4; ++cc) {
        float acc[16][4];
#pragma unroll
        for (int p = 0; p < 16; ++p)
#pragma unroll
            for (int j = 0; j < 4; ++j) acc[p][j] = 0.f;
#pragma unroll
        for (int ic = 0; ic < 3; ++ic) {
            float patch[36];
#pragma unroll
            for (int r = 0; r < 6; ++r)
#pragma unroll
                for (int q = 0; q < 6; ++q)
                    patch[r * 6 + q] = sP[ic * 4356 + (ph0 + r) * 66 + pw0 + q];
#pragma unroll
            for (int k = 0; k < 9; ++k) {
                int kr = k / 3, kc = k % 3;
                float4 wf = *(const float4*)&wsm[(ic * 9 + k) * 16 + cc * 4];
#pragma unroll
                for (int p = 0; p < 16; ++p) {
                    int pr = p >> 2, pc = p & 3;
                    float vv = patch[(pr + kr) * 6 + pc + kc];
                    acc[p][0] += vv * wf.x; acc[p][1] += vv * wf.y;
                    acc[p][2] += vv * wf.z; acc[p][3] += vv * wf.w;
                }
            }
        }
        float s_[4] = {0, 0, 0, 0}, q_[4] = {0, 0, 0, 0};
#pragma unroll
        for (int j = 0; j < 4; ++j) {
            float bj = b1[oc0 + cc * 4 + j];
#pragma unroll
            for (int p = 0; p < 16; ++p) {
                float a = acc[p][j] + bj;
                s_[j] += a; q_[j] += a * a;
            }
        }
#pragma unroll
        for (int j = 0; j < 4; ++j) {
#pragma unroll
            for (int m = 1; m < 64; m <<= 1) {
                s_[j] += __shfl_xor(s_[j], m);
                q_[j] += __shfl_xor(q_[j], m);
            }
            if (lane == 0) {
                atomicAdd(&accG[c * 64 + oc0 + cc * 4 + j], s_[j]);
                atomicAdd(&accG[1024 + c * 64 + oc0 + cc * 4 + j], q_[j]);
            }
        }
    }
}

__global__ void k_conv1_fin(const float* __restrict__ accG, const float* __restrict__ g1,
                            const float* __restrict__ be1, float* __restrict__ sc,
                            float* __restrict__ sh) {
    int e = blockIdx.x * 256 + threadIdx.x;
    if (e >= 1024) return;
    int oc = e & 63;
    float m = accG[e] * (1.f / 16384.f);
    float var = accG[1024 + e] * (1.f / 16384.f) - m * m;
    float s = g1[oc] * rsqrtf(var + 1e-5f);
    sc[e] = s;
    sh[e] = be1[oc] - m * s;
}

__global__ __launch_bounds__(256, 2) void k_conv1_apply2(
        const float* __restrict__ videos, const float* __restrict__ w1,
        const float* __restrict__ b1, const float* __restrict__ sc,
        const float* __restrict__ sh, float* __restrict__ x1p) {
    __shared__ float sP[3 * 66 * 66];
    __shared__ float wsm[3 * 9 * 16];
    int oc0 = blockIdx.x * 16, n = blockIdx.y;
    int c = n >> 2, b = n & 3;
    int tid = threadIdx.x;
    for (int e = tid; e < 3 * 66 * 66; e += 256) {
        int ic = e / 4356, rem = e % 4356;
        int r = rem / 66, col = rem % 66;
        float v = 0.f;
        if (r >= 1 && r <= 64 && col >= 1 && col <= 64)
            v = videos[((size_t)(b * 3 + ic) * 32 + 2 * c) * 4096 + (r - 1) * 64 + (col - 1)];
        sP[e] = v;
    }
    for (int e = tid; e < 432; e += 256) {
        int ic = e / 144, rem = e % 144, k = rem / 16, j = rem % 16;
        wsm[e] = w1[((size_t)((oc0 + j) * 3 + ic) * 3 + 1) * 9 + k];
    }
    __syncthreads();
    int ph0 = (tid >> 4) * 4, pw0 = (tid & 15) * 4;
    for (int cc = 0; cc < 4; ++cc) {
        float acc[16][4];
#pragma unroll
        for (int p = 0; p < 16; ++p)
#pragma unroll
            for (int j = 0; j < 4; ++j) acc[p][j] = 0.f;
#pragma unroll
        for (int ic = 0; ic < 3; ++ic) {
            float patch[36];
#pragma unroll
            for (int r = 0; r < 6; ++r)
#pragma unroll
                for (int q = 0; q < 6; ++q)
                    patch[r * 6 + q] = sP[ic * 4356 + (ph0 + r) * 66 + pw0 + q];
#pragma unroll
            for (int k = 0; k < 9; ++k) {
                int kr = k / 3, kc = k % 3;
                float4 wf = *(const float4*)&wsm[(ic * 9 + k) * 16 + cc * 4];
#pragma unroll
                for (int p = 0; p < 16; ++p) {
                    int pr = p >> 2, pc = p & 3;
                    float vv = patch[(pr + kr) * 6 + pc + kc];
                    acc[p][0] += vv * wf.x; acc[p][1] += vv * wf.y;
                    acc[p][2] += vv * wf.z; acc[p][3] += vv * wf.w;
                }
            }
        }
#pragma unroll
        for (int j = 0; j < 4; ++j) {
            int oc = oc0 + cc * 4 + j;
            float bj = b1[oc];
            float scj = sc[c * 64 + oc], shj = sh[c * 64 + oc];
#pragma unroll
            for (int pr2 = 0; pr2 < 2; ++pr2)
#pragma unroll
                for (int pc2 = 0; pc2 < 2; ++pc2) {
                    float m = -1e30f;
#pragma unroll
                    for (int dr = 0; dr < 2; ++dr)
#pragma unroll
                        for (int dc = 0; dc < 2; ++dc) {
                            int p = (pr2 * 2 + dr) * 4 + pc2 * 2 + dc;
                            float v = (acc[p][j] + bj) * scj + shj;
                            m = fmaxf(m, v);
                        }
                    int prow = (tid >> 4) * 2 + pr2, pcol = (tid & 15) * 2 + pc2;
                    x1p[((size_t)n * 64 + oc) * 1024 + prow * 32 + pcol] = fmaxf(m, 0.f);
                }
        }
    }
}

// ============================================================================
// conv2/conv3: 3x3 pad-1, LDS-staged padded input + weights, 16 oc + 2x2 px
// per thread. grid (OC/16, 64/NN), 256 threads.
// ============================================================================
template <int IC, int H, int W, int NN, int CH>
__global__ __launch_bounds__(256, 2) void k_conv(
        const float* __restrict__ in, const float* __restrict__ wt,
        const float* __restrict__ bias, float* __restrict__ out, int OC) {
    constexpr int PW = W + 2;
    constexpr int PLANE = (H + 2) * PW;
    constexpr int TI = CH * NN * PLANE;
    constexpr int THW = (H / 2) * (W / 2);
    __shared__ float sIn[TI];
    __shared__ float sW[CH * 144];
    int oc0 = blockIdx.x * 16, n0 = blockIdx.y * NN;
    int tid = threadIdx.x;
    int s = tid / THW, rem = tid % THW;
    int ph = rem / (W / 2), pw = rem % (W / 2);
    float acc[16][4];
#pragma unroll
    for (int j = 0; j < 16; ++j)
#pragma unroll
        for (int p = 0; p < 4; ++p) acc[j][p] = 0.f;

    for (int ic0 = 0; ic0 < IC; ic0 += CH) {
        __syncthreads();
        for (int e = tid; e < TI; e += 256) {
            int c = e / (NN * PLANE), r1 = e % (NN * PLANE);
            int ss = r1 / PLANE, r2 = r1 % PLANE;
            int r = r2 / PW, col = r2 % PW;
            float v = 0.f;
            if (r >= 1 && r <= H && col >= 1 && col <= W)
                v = in[((size_t)(n0 + ss) * IC + ic0 + c) * (H * W) + (r - 1) * W + (col - 1)];
            sIn[e] = v;
        }
        for (int e = tid; e < CH * 144; e += 256) {
            int c = e / 144, r1 = e % 144, k = r1 / 16, j = r1 % 16;
            sW[e] = wt[((size_t)(oc0 + j) * IC + ic0 + c) * 27 + 9 + k];
        }
        __syncthreads();
        for (int c = 0; c < CH; ++c) {
            const float* base = &sIn[((c * NN + s) * (H + 2) + 2 * ph) * PW + 2 * pw];
            float v[16];
#pragma unroll
            for (int r = 0; r < 4; ++r) {
                float2 t0 = *(const float2*)(base + r * PW);
                float2 t1 = *(const float2*)(base + r * PW + 2);
                v[r * 4 + 0] = t0.x; v[r * 4 + 1] = t0.y;
                v[r * 4 + 2] = t1.x; v[r * 4 + 3] = t1.y;
            }
#pragma unroll
            for (int k = 0; k < 9; ++k) {
                int kr = k / 3, kc = k % 3;
                float wv[16];
                *(float4*)&wv[0]  = *(const float4*)&sW[c * 144 + k * 16 + 0];
                *(float4*)&wv[4]  = *(const float4*)&sW[c * 144 + k * 16 + 4];
                *(float4*)&wv[8]  = *(const float4*)&sW[c * 144 + k * 16 + 8];
                *(float4*)&wv[12] = *(const float4*)&sW[c * 144 + k * 16 + 12];
#pragma unroll
                for (int p = 0; p < 4; ++p) {
                    int pr = p >> 1, pc = p & 1;
                    float vv = v[(pr + kr) * 4 + pc + kc];
#pragma unroll
                    for (int j = 0; j < 16; ++j) acc[j][p] += vv * wv[j];
                }
            }
        }
    }
#pragma unroll
    for (int j = 0; j < 16; ++j) {
        float bj = bias[oc0 + j];
#pragma unroll
        for (int p = 0; p < 4; ++p) {
            int pr = p >> 1, pc = p & 1;
            out[((size_t)(n0 + s) * OC + oc0 + j) * (H * W) + (2 * ph + pr) * W + 2 * pw + pc]
                = acc[j][p] + bj;
        }
    }
}

// per-(clip,channel) BN stats
__global__ void k_bn_stats(const float* __restrict__ buf, const float* __restrict__ g,
                           const float* __restrict__ be, float* __restrict__ scale,
                           float* __restrict__ shift, int C, int HW) {
    int c = blockIdx.x, ch = blockIdx.y, tid = threadIdx.x;
    float s = 0.f, s2 = 0.f;
    for (int b = 0; b < 4; ++b) {
        const float* p = buf + ((size_t)(c * 4 + b) * C + ch) * HW;
        for (int i = tid; i < HW; i += 256) { float v = p[i]; s += v; s2 += v * v; }
    }
    __shared__ float rs[256], rq[256];
    rs[tid] = s; rq[tid] = s2; __syncthreads();
    for (int k = 128; k > 0; k >>= 1) {
        if (tid < k) { rs[tid] += rs[tid + k]; rq[tid] += rq[tid + k]; }
        __syncthreads();
    }
    if (tid == 0) {
        float inv = 1.f / (float)(4 * HW);
        float m = rs[0] * inv, var = rq[0] * inv - m * m;
        float sc = g[ch] * rsqrtf(var + 1e-5f);
        scale[c * C + ch] = sc;
        shift[c * C + ch] = be[ch] - m * sc;
    }
}

__global__ void k_bn_apply_pool(const float* __restrict__ in, const float* __restrict__ scale,
                                const float* __restrict__ shift, float* __restrict__ out,
                                int C, int H, int W) {
    int OH = H >> 1, OW = W >> 1;
    size_t idx = (size_t)blockIdx.x * 256 + threadIdx.x;
    int ow = (int)(idx % OW);
    size_t r = idx / OW;
    int oh = (int)(r % OH); r /= OH;
    int ch = (int)(r % C);
    int n = (int)(r / C);
    int c = n >> 2;
    float sc = scale[c * C + ch], sh = shift[c * C + ch];
    const float* p = in + (((size_t)n * C + ch) * H + 2 * oh) * W + 2 * ow;
    float m = 0.f;
    m = fmaxf(m, p[0] * sc + sh);
    m = fmaxf(m, p[1] * sc + sh);
    m = fmaxf(m, p[W] * sc + sh);
    m = fmaxf(m, p[W + 1] * sc + sh);
    out[idx] = m;
}

// ---- R0-proven post-conv3 chain ----
__global__ void k_bn_apply_avgpool4(const float* __restrict__ in, const float* __restrict__ scale,
                                    const float* __restrict__ shift, float* __restrict__ out) {
    size_t idx = (size_t)blockIdx.x * 256 + threadIdx.x;  // 262,144
    int j = (int)(idx & 3), i = (int)(idx >> 2) & 3;
    int ch = (int)(idx >> 4) & 255, n = (int)(idx >> 12);
    int c = n >> 2;
    float sc = scale[c * 256 + ch], sh = shift[c * 256 + ch];
    const float* p = in + (((size_t)n * 256 + ch) * 16 + i * 4) * 16 + j * 4;
    float s = 0.f;
#pragma unroll
    for (int r = 0; r < 4; ++r)
#pragma unroll
        for (int q = 0; q < 4; ++q) s += fmaxf(p[r * 16 + q] * sc + sh, 0.f);
    out[idx] = s * (1.f / 16.f);
}

__global__ void k_tconv(const float* __restrict__ x3p, const float* __restrict__ tw,
                        const float* __restrict__ tb, float* __restrict__ y4) {
    size_t idx = (size_t)blockIdx.x * 256 + threadIdx.x;  // 262,144
    int p = (int)(idx & 15), o = (int)(idx >> 4) & 255, n = (int)(idx >> 12);
    const float* xr = x3p + (size_t)n * 4096 + p;
    float a = tb[o];
    for (int i = 0; i < 256; ++i) a += xr[i * 16] * tw[((size_t)o * 256 + i) * 3 + 1];
    y4[idx] = a;
}

__global__ void k_bn_apply(const float* __restrict__ in, const float* __restrict__ scale,
                           const float* __restrict__ shift, float* __restrict__ out) {
    size_t idx = (size_t)blockIdx.x * 256 + threadIdx.x;  // 262,144
    int ch = (int)(idx >> 4) & 255, n = (int)(idx >> 12);
    int c = n >> 2;
    float sc = scale[c * 256 + ch], sh = shift[c * 256 + ch];
    out[idx] = fmaxf(in[idx] * sc + sh, 0.f);
}

__global__ void k_proj(const float* __restrict__ x4, const float* __restrict__ pw,
                       const float* __restrict__ pb, float* __restrict__ feat) {
    int d0 = blockIdx.x * 8;
    int ro = threadIdx.x >> 2;
    int cp = threadIdx.x & 3;
    int c0 = d0 + cp * 2, c1 = c0 + 1;
    int n = (ro & 15) * 4 + (ro >> 4);
    const float* x = x4 + (size_t)n * 4096;
    const float* w0 = pw + (size_t)c0 * 4096;
    const float* w1 = pw + (size_t)c1 * 4096;
    float a0 = pb[c0], a1 = pb[c1];
    for (int k = 0; k < 4096; ++k) { float f = x[k]; a0 += f * w0[k]; a1 += f * w1[k]; }
    feat[(size_t)ro * 512 + c0] = a0;
    feat[(size_t)ro * 512 + c1] = a1;
}

__global__ void k_vq(const float* __restrict__ feat, const float* __restrict__ cb,
                     float* __restrict__ quant, float* __restrict__ acc) {
    int row = blockIdx.x, tid = threadIdx.x;
    __shared__ float f[512];
    for (int k = tid; k < 512; k += 256) f[k] = feat[(size_t)row * 512 + k];
    __syncthreads();
    float best = 3.4e38f; int bidx = 0;
    for (int j = tid; j < 1024; j += 256) {
        const float* c = cb + (size_t)j * 512;
        float d2 = 0.f;
        for (int k = 0; k < 512; ++k) { float t = f[k] - c[k]; d2 += t * t; }
        if (d2 < best) { best = d2; bidx = j; }
    }
    __shared__ float rd[256]; __shared__ int ri[256];
    rd[tid] = best; ri[tid] = bidx; __syncthreads();
    for (int k = 128; k > 0; k >>= 1) {
        if (tid < k) {
            float od = rd[tid + k]; int oi = ri[tid + k];
            if (od < rd[tid] || (od == rd[tid] && oi < ri[tid])) { rd[tid] = od; ri[tid] = oi; }
        }
        __syncthreads();
    }
    __shared__ int wsel;
    if (tid == 0) { wsel = ri[0]; atomicAdd(acc, rd[0]); }
    __syncthreads();
    const float* c = cb + (size_t)wsel * 512;
    for (int k = tid; k < 512; k += 256) quant[(size_t)row * 512 + k] = c[k];
}

// gi = X @ w_ih.T + b_ih, rows (b, t) t=0..14; X and gi rows at stride-16 (b*16+t)
__global__ void k_gru_gi(const float* __restrict__ x, const float* __restrict__ wih,
                         const float* __restrict__ bih, float* __restrict__ gi) {
    int r = blockIdx.x;  // 0..59
    int b = r / 15, t = r % 15;
    const float* xr = x + ((size_t)(b * 16 + t)) * 512;
    __shared__ float xsRow[512];
    for (int k = threadIdx.x; k < 512; k += 256) xsRow[k] = xr[k];
    __syncthreads();
    for (int d = threadIdx.x; d < 1536; d += 256) {
        const float* wr = wih + (size_t)d * 512;
        float a = bih[d];
        for (int k = 0; k < 512; ++k) a += xsRow[k] * wr[k];
        gi[((size_t)(b * 16 + t)) * 1536 + d] = a;
    }
}

// One GRU step: grid 128 (4 h-dims each), wave = one h-dim, float4 rows.
__global__ void k_gru_step2(const float* __restrict__ gi, const float* __restrict__ whh,
                            const float* __restrict__ bhh, float* __restrict__ hseq, int t) {
    int wv = threadIdx.x >> 6, lane = threadIdx.x & 63;
    int d = blockIdx.x * 4 + wv;
    const float4* w0p = (const float4*)(whh + (size_t)d * 512);
    const float4* w1p = (const float4*)(whh + (size_t)(512 + d) * 512);
    const float4* w2p = (const float4*)(whh + (size_t)(1024 + d) * 512);
    float4 w0a = w0p[lane * 2], w0b = w0p[lane * 2 + 1];
    float4 w1a = w1p[lane * 2], w1b = w1p[lane * 2 + 1];
    float4 w2a = w2p[lane * 2], w2b = w2p[lane * 2 + 1];
    float bh0 = bhh[d], bh1 = bhh[512 + d], bh2 = bhh[1024 + d];
    for (int b = 0; b < 4; ++b) {
        float4 ha = make_float4(0, 0, 0, 0), hb = ha;
        float hpd = 0.f;
        if (t > 0) {
            const float4* hp = (const float4*)(hseq + (size_t)(b * 16 + t - 1) * 512);
            ha = hp[lane * 2]; hb = hp[lane * 2 + 1];
            hpd = hseq[(size_t)(b * 16 + t - 1) * 512 + d];
        }
        float s0 = w0a.x * ha.x + w0a.y * ha.y + w0a.z * ha.z + w0a.w * ha.w
                 + w0b.x * hb.x + w0b.y * hb.y + w0b.z * hb.z + w0b.w * hb.w;
        float s1 = w1a.x * ha.x + w1a.y * ha.y + w1a.z * ha.z + w1a.w * ha.w
                 + w1b.x * hb.x + w1b.y * hb.y + w1b.z * hb.z + w1b.w * hb.w;
        float s2 = w2a.x * ha.x + w2a.y * ha.y + w2a.z * ha.z + w2a.w * ha.w
                 + w2b.x * hb.x + w2b.y * hb.y + w2b.z * hb.z + w2b.w * hb.w;
#pragma unroll
        for (int m = 1; m < 64; m <<= 1) {
            s0 += __shfl_xor(s0, m);
            s1 += __shfl_xor(s1, m);
            s2 += __shfl_xor(s2, m);
        }
        const float* gr = gi + (size_t)(b * 16 + t) * 1536;
        float rr = 1.f / (1.f + expf(-(gr[d] + s0 + bh0)));
        float zz = 1.f / (1.f + expf(-(gr[512 + d] + s1 + bh1)));
        float nn = tanhf(gr[1024 + d] + rr * (s2 + bh2));
        if (lane == 0)
            hseq[(size_t)(b * 16 + t) * 512 + d] = (1.f - zz) * nn + zz * hpd;
    }
}

__global__ void k_ctx_loss(const float* __restrict__ h2, const float* __restrict__ feat,
                           float* __restrict__ acc) {
    int tid = threadIdx.x;
    size_t idx = (size_t)blockIdx.x * 256 + tid;  // 30720
    int d = (int)(idx & 511);
    int rt = (int)(idx >> 9);
    int t = rt % 15, b = rt / 15;
    float diff = h2[(size_t)(b * 16 + t) * 512 + d] - feat[(size_t)(b * 16 + t + 1) * 512 + d];
    float v = diff * diff;
#pragma unroll
    for (int m = 1; m < 64; m <<= 1) v += __shfl_xor(v, m);
    __shared__ float ws[4];
    if ((tid & 63) == 0) ws[tid >> 6] = v;
    __syncthreads();
    if (tid == 0) atomicAdd(acc + 1, ws[0] + ws[1] + ws[2] + ws[3]);
}

__global__ void k_word_vq(const float* __restrict__ quant, const float* __restrict__ wcb,
                          float* __restrict__ wemb, float* __restrict__ out_widx) {
    int row = blockIdx.x;  // b*8+wi
    int b = row >> 3, wi = row & 7;
    int tid = threadIdx.x;
    __shared__ float f[512];
    for (int k = tid; k < 512; k += 256)
        f[k] = 0.5f * (quant[(size_t)(b * 16 + 2 * wi) * 512 + k] +
                       quant[(size_t)(b * 16 + 2 * wi + 1) * 512 + k]);
    __syncthreads();
    const float* cp = wcb + (size_t)tid * 512;
    float d2 = 0.f;
    for (int k = 0; k < 512; ++k) { float t = f[k] - cp[k]; d2 += t * t; }
    __shared__ float rd[256]; __shared__ int ri[256];
    rd[tid] = d2; ri[tid] = tid; __syncthreads();
    for (int k = 128; k > 0; k >>= 1) {
        if (tid < k) {
            float od = rd[tid + k]; int oi = ri[tid + k];
            if (od < rd[tid] || (od == rd[tid] && oi < ri[tid])) { rd[tid] = od; ri[tid] = oi; }
        }
        __syncthreads();
    }
    __shared__ int wsel;
    if (tid == 0) { wsel = ri[0]; out_widx[row] = (float)ri[0]; }
    __syncthreads();
    const float* cb = wcb + (size_t)wsel * 512;
    for (int k = tid; k < 512; k += 256) wemb[(size_t)row * 512 + k] = cb[k];
}

__global__ void k_align(const float* __restrict__ wemb, const float* __restrict__ aw,
                        const float* __restrict__ ab, float* __restrict__ acc) {
    int row = blockIdx.x, tid = threadIdx.x;
    __shared__ float e[512];
    for (int k = tid; k < 512; k += 256) e[k] = wemb[(size_t)row * 512 + k];
    __syncthreads();
    float local = 0.f;
    for (int d = tid; d < 512; d += 256) {
        const float* wr = aw + (size_t)d * 512;
        float a = ab[d] - e[d];
        for (int k = 0; k < 512; ++k) a += e[k] * wr[k];
        local += a * a;
    }
    __shared__ float rs[256];
    rs[tid] = local; __syncthreads();
    for (int k = 128; k > 0; k >>= 1) { if (tid < k) rs[tid] += rs[tid + k]; __syncthreads(); }
    if (tid == 0) atomicAdd(acc + 2, rs[0]);
}

__global__ void k_ctx(const float* __restrict__ wemb, float* __restrict__ ctx) {
    int e = blockIdx.x * 256 + threadIdx.x;  // 2048
    int b = e >> 9, d = e & 511;
    float s = 0.f;
#pragma unroll
    for (int wi = 0; wi < 8; ++wi) s += wemb[(size_t)(b * 8 + wi) * 512 + d];
    ctx[e] = s * 0.125f;
}

// small-M (M=4) GEMV: C[4,N] = A[4,K] @ B[N,K]^T + bias, optional relu.
__global__ void k_smallM(const float* __restrict__ A, const float* __restrict__ B,
                         const float* __restrict__ bias, float* __restrict__ C,
                         int N, int K, int relu) {
    __shared__ float xs[4096];
    int tid = threadIdx.x;
    for (int e = tid; e < 4 * K; e += 256) xs[e] = A[e];
    __syncthreads();
    int r = tid >> 4, kt = tid & 15;
    int n = blockIdx.x * 16 + r;
    float acc[4] = {0, 0, 0, 0};
    if (n < N) {
        int iters = K >> 6;
        for (int i = 0; i < iters; ++i) {
            int k = i * 64 + kt * 4;
            float4 w = *(const float4*)&B[(size_t)n * K + k];
#pragma unroll
            for (int b = 0; b < 4; ++b) {
                float4 x = *(const float4*)&xs[b * K + k];
                acc[b] += w.x * x.x + w.y * x.y + w.z * x.z + w.w * x.w;
            }
        }
    }
#pragma unroll
    for (int b = 0; b < 4; ++b) {
#pragma unroll
        for (int m = 1; m < 16; m <<= 1) acc[b] += __shfl_xor(acc[b], m);
    }
    if (kt == 0 && n < N) {
#pragma unroll
        for (int b = 0; b < 4; ++b) {
            float v = acc[b] + bias[n];
            if (relu) v = fmaxf(v, 0.f);
            C[(size_t)b * N + n] = v;
        }
    }
}

__global__ void k_final(const float* __restrict__ logits, const int* __restrict__ tokens,
                        const float* __restrict__ acc, float* __restrict__ out_total) {
    int tid = threadIdx.x;
    __shared__ float rs[256];
    __shared__ float sM;
    float tr = 0.f;
    for (int b = 0; b < 4; ++b) {
        const float* lg = logits + (size_t)b * 3000;
        float m = -1e30f;
        for (int d = tid; d < 3000; d += 256) m = fmaxf(m, lg[d]);
        rs[tid] = m; __syncthreads();
        for (int k = 128; k > 0; k >>= 1) { if (tid < k) rs[tid] = fmaxf(rs[tid], rs[tid + k]); __syncthreads(); }
        if (tid == 0) sM = rs[0];
        __syncthreads();
        float M = sM;
        float s = 0.f;
        for (int d = tid; d < 3000; d += 256) s += expf(lg[d] - M);
        rs[tid] = s; __syncthreads();
        for (int k = 128; k > 0; k >>= 1) { if (tid < k) rs[tid] += rs[tid + k]; __syncthreads(); }
        if (tid == 0) {
            int t0 = tokens[b * 10];
            tr += -(lg[t0] - M - logf(rs[0]));
        }
        __syncthreads();
    }
    if (tid == 0) {
        float total = 1.25f * acc[0] * (1.f / 32768.f)
                    + 0.1f  * acc[1] * (1.f / 30720.f)
                    + 0.1f  * acc[2] * (1.f / 16384.f)
                    + tr;
        *out_total = total;
    }
}

extern "C" void kernel_launch(void* const* d_in, const int* in_sizes, int n_in,
                              void* d_out, int out_size, void* d_ws, size_t ws_size,
                              hipStream_t stream) {
    (void)in_sizes; (void)n_in; (void)out_size; (void)ws_size;
    const float* videos   = (const float*)d_in[0];
    const float* conv1_w  = (const float*)d_in[1];
    const float* conv1_b  = (const float*)d_in[2];
    const float* bn1_g    = (const float*)d_in[3];
    const float* bn1_b    = (const float*)d_in[4];
    const float* conv2_w  = (const float*)d_in[5];
    const float* conv2_b  = (const float*)d_in[6];
    const float* bn2_g    = (const float*)d_in[7];
    const float* bn2_b    = (const float*)d_in[8];
    const float* conv3_w  = (const float*)d_in[9];
    const float* conv3_b  = (const float*)d_in[10];
    const float* bn3_g    = (const float*)d_in[11];
    const float* bn3_b    = (const float*)d_in[12];
    const float* tconv_w  = (const float*)d_in[13];
    const float* tconv_b  = (const float*)d_in[14];
    const float* bn4_g    = (const float*)d_in[15];
    const float* bn4_b    = (const float*)d_in[16];
    const float* proj_w   = (const float*)d_in[17];
    const float* proj_b   = (const float*)d_in[18];
    const float* codebook = (const float*)d_in[19];
    const float* word_cb  = (const float*)d_in[20];
    const float* align_w  = (const float*)d_in[21];
    const float* align_b  = (const float*)d_in[22];
    const float* gru_wih0 = (const float*)d_in[23];
    const float* gru_whh0 = (const float*)d_in[24];
    const float* gru_bih0 = (const float*)d_in[25];
    const float* gru_bhh0 = (const float*)d_in[26];
    const float* gru_wih1 = (const float*)d_in[27];
    const float* gru_whh1 = (const float*)d_in[28];
    const float* gru_bih1 = (const float*)d_in[29];
    const float* gru_bhh1 = (const float*)d_in[30];
    const float* dec1_w   = (const float*)d_in[31];
    const float* dec1_b   = (const float*)d_in[32];
    const float* dec2_w   = (const float*)d_in[33];
    const float* dec2_b   = (const float*)d_in[34];
    const float* dec3_w   = (const float*)d_in[35];
    const float* dec3_b   = (const float*)d_in[36];
    const int*   tokens   = (const int*)d_in[37];

    float* wsf   = (float*)d_ws;
    float* out   = (float*)d_out;
    float* x1p   = wsf + OFF_X1P;
    float* x2p   = wsf + OFF_X2P;
    float* y2    = wsf + OFF_Y2;
    float* y3    = wsf + OFF_Y3;
    float* x3p   = wsf + OFF_X3P;
    float* y4    = wsf + OFF_Y4;
    float* x4    = wsf + OFF_X4;
    float* feat  = wsf + OFF_FEAT;
    float* quant = wsf + OFF_QUANT;
    float* gi1   = wsf + OFF_GI1;
    float* gi2   = wsf + OFF_GI2;
    float* h1    = wsf + OFF_H1;
    float* h2    = wsf + OFF_H2;
    float* wemb  = wsf + OFF_WEMB;
    float* ctx   = wsf + OFF_CTX;
    float* hh1   = wsf + OFF_HH1;
    float* hh2   = wsf + OFF_HH2;
    float* logit = wsf + OFF_LOG;
    float* sc    = wsf + OFF_SC;
    float* sh    = wsf + OFF_SH;
    float* accG  = wsf + OFF_ACCG;
    float* accv  = wsf + OFF_ACC;

    k_zero_zone<<<(int)((ZONE_LEN + 255) / 256), 256, 0, stream>>>(wsf + ZONE_BEG, (int)ZONE_LEN);

    // conv1 + bn1 + pool
    k_conv1_stats2<<<dim3(4, 64), 256, 0, stream>>>(videos, conv1_w, conv1_b, accG);
    k_conv1_fin<<<4, 256, 0, stream>>>(accG, bn1_g, bn1_b, sc, sh);
    k_conv1_apply2<<<dim3(4, 64), 256, 0, stream>>>(videos, conv1_w, conv1_b, sc, sh, x1p);
    // conv2 + bn2 + pool
    k_conv<64, 32, 32, 1, 8><<<dim3(8, 64), 256, 0, stream>>>(x1p, conv2_w, conv2_b, y2, 128);
    k_bn_stats<<<dim3(16, 128), 256, 0, stream>>>(y2, bn2_g, bn2_b, sc, sh, 128, 1024);
    k_bn_apply_pool<<<8192, 256, 0, stream>>>(y2, sc, sh, x2p, 128, 32, 32);
    // conv3 + bn3 + R0 chain
    k_conv<128, 16, 16, 4, 8><<<dim3(16, 16), 256, 0, stream>>>(x2p, conv3_w, conv3_b, y3, 256);
    k_bn_stats<<<dim3(16, 256), 256, 0, stream>>>(y3, bn3_g, bn3_b, sc, sh, 256, 256);
    k_bn_apply_avgpool4<<<1024, 256, 0, stream>>>(y3, sc, sh, x3p);
    k_tconv<<<1024, 256, 0, stream>>>(x3p, tconv_w, tconv_b, y4);
    k_bn_stats<<<dim3(16, 256), 256, 0, stream>>>(y4, bn4_g, bn4_b, sc, sh, 256, 16);
    k_bn_apply<<<1024, 256, 0, stream>>>(y4, sc, sh, x4);
    k_proj<<<64, 256, 0, stream>>>(x4, proj_w, proj_b, feat);
    k_vq<<<64, 256, 0, stream>>>(feat, codebook, quant, accv);
    // GRU layer 1
    k_gru_gi<<<60, 256, 0, stream>>>(quant, gru_wih0, gru_bih0, gi1);
    for (int t = 0; t < 15; ++t)
        k_gru_step2<<<128, 256, 0, stream>>>(gi1, gru_whh0, gru_bhh0, h1, t);
    // GRU layer 2
    k_gru_gi<<<60, 256, 0, stream>>>(h1, gru_wih1, gru_bih1, gi2);
    for (int t = 0; t < 15; ++t)
        k_gru_step2<<<128, 256, 0, stream>>>(gi2, gru_whh1, gru_bhh1, h2, t);
    k_ctx_loss<<<120, 256, 0, stream>>>(h2, feat, accv);
    // word VQ + alignment
    k_word_vq<<<32, 256, 0, stream>>>(quant, word_cb, wemb, out);
    k_align<<<32, 256, 0, stream>>>(wemb, align_w, align_b, accv);
    // decoder
    k_ctx<<<8, 256, 0, stream>>>(wemb, ctx);
    k_smallM<<<32, 256, 0, stream>>>(ctx, dec1_w, dec1_b, hh1, 512, 512, 1);
    k_smallM<<<64, 256, 0, stream>>>(hh1, dec2_w, dec2_b, hh2, 1024, 512, 1);
    k_smallM<<<188, 256, 0, stream>>>(hh2, dec3_w, dec3_b, logit, 3000, 1024, 0);
    k_final<<<1, 256, 0, stream>>>(logit, tokens, accv, out + 32);
}

// Round 6
// 1519.819 us; speedup vs baseline: 1.9542x; 1.1262x over previous
//
#include <hip/hip_runtime.h>

// ============================================================================
// SignLLM forward, fp32. B=4, T=32 -> nc=16 clips, D=512.
// Output: d_out[0..31] = widx (4,8) as float, d_out[32] = total loss.
// R5: R4 kernels + FULLY DETERMINISTIC reductions (no float atomics anywhere).
// R4's tripwire failure = run-to-run nondeterminism from atomicAdd ordering
// (conv1 BN stats + loss accumulators). Partials now land in fixed slots and
// are summed in fixed order.
// ============================================================================

// ---- workspace layout (float offsets), peak ~12.60M floats = 50.4 MB ----
static const size_t OFF_X1P  = 0;         // (64,64,32,32)  4,194,304  [dead after conv2]
static const size_t OFF_Y2   = 4194304;   // (64,128,32,32) 8,388,608  -> ends 12,582,912
static const size_t OFF_X2P  = 0;         // (64,128,16,16) 2,097,152  [x1p dead]
static const size_t OFF_Y3   = 4194304;   // (64,256,16,16) 4,194,304  [y2 dead]
// tail block in [2097152, 4194304): x1p dead by the time these are written
static const size_t OFF_X3P  = 2097152;   // 262,144
static const size_t OFF_Y4   = 2359296;   // 262,144
static const size_t OFF_X4   = 2621440;   // 262,144
static const size_t OFF_FEAT = 2883584;   // (64,512) 32,768
static const size_t OFF_QUANT= 2916352;   // 32,768
static const size_t OFF_GI1  = 2949120;   // (64,1536) 98,304 (rows b*16+t)
static const size_t OFF_GI2  = 3047424;   // 98,304
static const size_t OFF_H1   = 3145728;   // (64,512) rows b*16+t
static const size_t OFF_H2   = 3178496;   // 32,768
static const size_t OFF_WEMB = 3211264;   // (32,512) 16,384
static const size_t OFF_CTX  = 3227648;   // 2,048
static const size_t OFF_HH1  = 3229696;   // 2,048
static const size_t OFF_HH2  = 3231744;   // 4,096
static const size_t OFF_LOG  = 3235840;   // 12,000 -> ends 3,247,840
// long-lived block PAST y2's end (12,582,912):
static const size_t OFF_SC    = 12582912; // 4,096
static const size_t OFF_SH    = 12587008; // 4,096
static const size_t OFF_ACCP  = 12591104; // 8,192: conv1 partials (sum, then sq)
static const size_t OFF_COMMIT= 12599296; // 64
static const size_t OFF_CTXA  = 12599360; // 120
static const size_t OFF_ALIGNA= 12599480; // 32 -> ends 12,599,512

// ============================================================================
// conv1 (IC=3, 64x64, pad 1, mid temporal slice). Plane in LDS, 6x6 patch in
// regs, 16 oc/block. grid (4 ocg, 64 n), 256 thr; thread = 4x4 positions.
// Stats: deterministic — per-block partial per (c,oc) -> accP[(c*64+oc)*4+b].
// ============================================================================
__global__ __launch_bounds__(256, 2) void k_conv1_stats2(
        const float* __restrict__ videos, const float* __restrict__ w1,
        const float* __restrict__ b1, float* __restrict__ accP) {
    __shared__ float sP[3 * 66 * 66];
    __shared__ float wsm[3 * 9 * 16];
    __shared__ float sRed[4][4], qRed[4][4];  // [wave][j]
    int oc0 = blockIdx.x * 16, n = blockIdx.y;
    int c = n >> 2, b = n & 3;
    int tid = threadIdx.x;
    for (int e = tid; e < 3 * 66 * 66; e += 256) {
        int ic = e / 4356, rem = e % 4356;
        int r = rem / 66, col = rem % 66;
        float v = 0.f;
        if (r >= 1 && r <= 64 && col >= 1 && col <= 64)
            v = videos[((size_t)(b * 3 + ic) * 32 + 2 * c) * 4096 + (r - 1) * 64 + (col - 1)];
        sP[e] = v;
    }
    for (int e = tid; e < 432; e += 256) {
        int ic = e / 144, rem = e % 144, k = rem / 16, j = rem % 16;
        wsm[e] = w1[((size_t)((oc0 + j) * 3 + ic) * 3 + 1) * 9 + k];
    }
    __syncthreads();
    int ph0 = (tid >> 4) * 4, pw0 = (tid & 15) * 4;
    int lane = tid & 63, wave = tid >> 6;
    for (int cc = 0; cc < 4; ++cc) {
        float acc[16][4];
#pragma unroll
        for (int p = 0; p < 16; ++p)
#pragma unroll
            for (int j = 0; j < 4; ++j) acc[p][j] = 0.f;
#pragma unroll
        for (int ic = 0; ic < 3; ++ic) {
            float patch[36];
#pragma unroll
            for (int r = 0; r < 6; ++r)
#pragma unroll
                for (int q = 0; q < 6; ++q)
                    patch[r * 6 + q] = sP[ic * 4356 + (ph0 + r) * 66 + pw0 + q];
#pragma unroll
            for (int k = 0; k < 9; ++k) {
                int kr = k / 3, kc = k % 3;
                float4 wf = *(const float4*)&wsm[(ic * 9 + k) * 16 + cc * 4];
#pragma unroll
                for (int p = 0; p < 16; ++p) {
                    int pr = p >> 2, pc = p & 3;
                    float vv = patch[(pr + kr) * 6 + pc + kc];
                    acc[p][0] += vv * wf.x; acc[p][1] += vv * wf.y;
                    acc[p][2] += vv * wf.z; acc[p][3] += vv * wf.w;
                }
            }
        }
        float s_[4] = {0, 0, 0, 0}, q_[4] = {0, 0, 0, 0};
#pragma unroll
        for (int j = 0; j < 4; ++j) {
            float bj = b1[oc0 + cc * 4 + j];
#pragma unroll
            for (int p = 0; p < 16; ++p) {
                float a = acc[p][j] + bj;
                s_[j] += a; q_[j] += a * a;
            }
        }
#pragma unroll
        for (int j = 0; j < 4; ++j) {
#pragma unroll
            for (int m = 1; m < 64; m <<= 1) {
                s_[j] += __shfl_xor(s_[j], m);
                q_[j] += __shfl_xor(q_[j], m);
            }
            if (lane == 0) { sRed[wave][j] = s_[j]; qRed[wave][j] = q_[j]; }
        }
        __syncthreads();
        if (tid < 4) {  // j = tid
            float s = ((sRed[0][tid] + sRed[1][tid]) + (sRed[2][tid] + sRed[3][tid]));
            float q = ((qRed[0][tid] + qRed[1][tid]) + (qRed[2][tid] + qRed[3][tid]));
            int oc = oc0 + cc * 4 + tid;
            accP[((size_t)(c * 64 + oc)) * 4 + b] = s;
            accP[4096 + ((size_t)(c * 64 + oc)) * 4 + b] = q;
        }
        __syncthreads();
    }
}

__global__ void k_conv1_fin(const float* __restrict__ accP, const float* __restrict__ g1,
                            const float* __restrict__ be1, float* __restrict__ sc,
                            float* __restrict__ sh) {
    int e = blockIdx.x * 256 + threadIdx.x;
    if (e >= 1024) return;
    int oc = e & 63;
    const float* ps = accP + (size_t)e * 4;
    const float* pq = accP + 4096 + (size_t)e * 4;
    float s = ((ps[0] + ps[1]) + (ps[2] + ps[3]));
    float q = ((pq[0] + pq[1]) + (pq[2] + pq[3]));
    float m = s * (1.f / 16384.f);
    float var = q * (1.f / 16384.f) - m * m;
    float sf = g1[oc] * rsqrtf(var + 1e-5f);
    sc[e] = sf;
    sh[e] = be1[oc] - m * sf;
}

__global__ __launch_bounds__(256, 2) void k_conv1_apply2(
        const float* __restrict__ videos, const float* __restrict__ w1,
        const float* __restrict__ b1, const float* __restrict__ sc,
        const float* __restrict__ sh, float* __restrict__ x1p) {
    __shared__ float sP[3 * 66 * 66];
    __shared__ float wsm[3 * 9 * 16];
    int oc0 = blockIdx.x * 16, n = blockIdx.y;
    int c = n >> 2, b = n & 3;
    int tid = threadIdx.x;
    for (int e = tid; e < 3 * 66 * 66; e += 256) {
        int ic = e / 4356, rem = e % 4356;
        int r = rem / 66, col = rem % 66;
        float v = 0.f;
        if (r >= 1 && r <= 64 && col >= 1 && col <= 64)
            v = videos[((size_t)(b * 3 + ic) * 32 + 2 * c) * 4096 + (r - 1) * 64 + (col - 1)];
        sP[e] = v;
    }
    for (int e = tid; e < 432; e += 256) {
        int ic = e / 144, rem = e % 144, k = rem / 16, j = rem % 16;
        wsm[e] = w1[((size_t)((oc0 + j) * 3 + ic) * 3 + 1) * 9 + k];
    }
    __syncthreads();
    int ph0 = (tid >> 4) * 4, pw0 = (tid & 15) * 4;
    for (int cc = 0; cc < 4; ++cc) {
        float acc[16][4];
#pragma unroll
        for (int p = 0; p < 16; ++p)
#pragma unroll
            for (int j = 0; j < 4; ++j) acc[p][j] = 0.f;
#pragma unroll
        for (int ic = 0; ic < 3; ++ic) {
            float patch[36];
#pragma unroll
            for (int r = 0; r < 6; ++r)
#pragma unroll
                for (int q = 0; q < 6; ++q)
                    patch[r * 6 + q] = sP[ic * 4356 + (ph0 + r) * 66 + pw0 + q];
#pragma unroll
            for (int k = 0; k < 9; ++k) {
                int kr = k / 3, kc = k % 3;
                float4 wf = *(const float4*)&wsm[(ic * 9 + k) * 16 + cc * 4];
#pragma unroll
                for (int p = 0; p < 16; ++p) {
                    int pr = p >> 2, pc = p & 3;
                    float vv = patch[(pr + kr) * 6 + pc + kc];
                    acc[p][0] += vv * wf.x; acc[p][1] += vv * wf.y;
                    acc[p][2] += vv * wf.z; acc[p][3] += vv * wf.w;
                }
            }
        }
#pragma unroll
        for (int j = 0; j < 4; ++j) {
            int oc = oc0 + cc * 4 + j;
            float bj = b1[oc];
            float scj = sc[c * 64 + oc], shj = sh[c * 64 + oc];
#pragma unroll
            for (int pr2 = 0; pr2 < 2; ++pr2)
#pragma unroll
                for (int pc2 = 0; pc2 < 2; ++pc2) {
                    float m = -1e30f;
#pragma unroll
                    for (int dr = 0; dr < 2; ++dr)
#pragma unroll
                        for (int dc = 0; dc < 2; ++dc) {
                            int p = (pr2 * 2 + dr) * 4 + pc2 * 2 + dc;
                            float v = (acc[p][j] + bj) * scj + shj;
                            m = fmaxf(m, v);
                        }
                    int prow = (tid >> 4) * 2 + pr2, pcol = (tid & 15) * 2 + pc2;
                    x1p[((size_t)n * 64 + oc) * 1024 + prow * 32 + pcol] = fmaxf(m, 0.f);
                }
        }
    }
}

// ============================================================================
// conv2: IC=64, 32x32, OC=128. Block = 1 clip x 16-row slab x 16 oc.
// grid (8, 2, 64) = 1024 blocks. LDS row stride 35 (odd).
// ============================================================================
__global__ __launch_bounds__(256) void k_conv2(
        const float* __restrict__ in, const float* __restrict__ wt,
        const float* __restrict__ bias, float* __restrict__ out) {
    __shared__ float sIn[8 * 18 * 35];   // 5040 floats
    __shared__ float sW[8 * 144];        // 1152 floats
    int oc0 = blockIdx.x * 16, r0 = blockIdx.y * 16, n = blockIdx.z;
    int tid = threadIdx.x;
    int row = tid >> 4, cp = tid & 15;
    float acc[16][2];
#pragma unroll
    for (int j = 0; j < 16; ++j) { acc[j][0] = 0.f; acc[j][1] = 0.f; }

    for (int ic0 = 0; ic0 < 64; ic0 += 8) {
        __syncthreads();
        for (int e = tid; e < 5040; e += 256) {
            int ch = e / 630, rem = e % 630;
            int r = rem / 35, col = rem % 35;
            int gr = r0 - 1 + r, gc = col - 1;
            float v = 0.f;
            if (gr >= 0 && gr < 32 && gc >= 0 && gc < 32)
                v = in[((size_t)(n * 64 + ic0 + ch) * 32 + gr) * 32 + gc];
            sIn[e] = v;
        }
        for (int e = tid; e < 1152; e += 256) {
            int c = e / 144, r1 = e % 144, k = r1 / 16, j = r1 % 16;
            sW[e] = wt[((size_t)(oc0 + j) * 64 + ic0 + c) * 27 + 9 + k];
        }
        __syncthreads();
        for (int c = 0; c < 8; ++c) {
            const float* base = &sIn[c * 630 + row * 35 + 2 * cp];
            float v[3][4];
#pragma unroll
            for (int r = 0; r < 3; ++r)
#pragma unroll
                for (int q = 0; q < 4; ++q) v[r][q] = base[r * 35 + q];
#pragma unroll
            for (int k = 0; k < 9; ++k) {
                int kr = k / 3, kc = k % 3;
                float wv[16];
                *(float4*)&wv[0]  = *(const float4*)&sW[c * 144 + k * 16 + 0];
                *(float4*)&wv[4]  = *(const float4*)&sW[c * 144 + k * 16 + 4];
                *(float4*)&wv[8]  = *(const float4*)&sW[c * 144 + k * 16 + 8];
                *(float4*)&wv[12] = *(const float4*)&sW[c * 144 + k * 16 + 12];
                float v0 = v[kr][kc], v1 = v[kr][kc + 1];
#pragma unroll
                for (int j = 0; j < 16; ++j) {
                    acc[j][0] += v0 * wv[j];
                    acc[j][1] += v1 * wv[j];
                }
            }
        }
    }
#pragma unroll
    for (int j = 0; j < 16; ++j) {
        float bj = bias[oc0 + j];
        float2 o2 = make_float2(acc[j][0] + bj, acc[j][1] + bj);
        *(float2*)&out[((size_t)(n * 128 + oc0 + j) * 32 + r0 + row) * 32 + 2 * cp] = o2;
    }
}

// ============================================================================
// conv3: IC=128, 16x16, OC=256. Block = 1 clip x full plane x 16 oc.
// grid (16, 64) = 1024 blocks. LDS stride 19.
// ============================================================================
__global__ __launch_bounds__(256) void k_conv3k(
        const float* __restrict__ in, const float* __restrict__ wt,
        const float* __restrict__ bias, float* __restrict__ out) {
    __shared__ float sIn[8 * 18 * 19];   // 2736 floats
    __shared__ float sW[8 * 144];
    int oc0 = blockIdx.x * 16, n = blockIdx.y;
    int tid = threadIdx.x;
    int row = tid >> 4, col = tid & 15;
    float acc[16];
#pragma unroll
    for (int j = 0; j < 16; ++j) acc[j] = 0.f;

    for (int ic0 = 0; ic0 < 128; ic0 += 8) {
        __syncthreads();
        for (int e = tid; e < 2736; e += 256) {
            int ch = e / 342, rem = e % 342;
            int r = rem / 19, cc = rem % 19;
            int gr = r - 1, gc = cc - 1;
            float v = 0.f;
            if (gr >= 0 && gr < 16 && gc >= 0 && gc < 16)
                v = in[((size_t)(n * 128 + ic0 + ch) * 16 + gr) * 16 + gc];
            sIn[e] = v;
        }
        for (int e = tid; e < 1152; e += 256) {
            int c = e / 144, r1 = e % 144, k = r1 / 16, j = r1 % 16;
            sW[e] = wt[((size_t)(oc0 + j) * 128 + ic0 + c) * 27 + 9 + k];
        }
        __syncthreads();
        for (int c = 0; c < 8; ++c) {
            const float* base = &sIn[c * 342 + row * 19 + col];
            float v[3][3];
#pragma unroll
            for (int r = 0; r < 3; ++r)
#pragma unroll
                for (int q = 0; q < 3; ++q) v[r][q] = base[r * 19 + q];
#pragma unroll
            for (int k = 0; k < 9; ++k) {
                float vv = v[k / 3][k % 3];
                float wv[16];
                *(float4*)&wv[0]  = *(const float4*)&sW[c * 144 + k * 16 + 0];
                *(float4*)&wv[4]  = *(const float4*)&sW[c * 144 + k * 16 + 4];
                *(float4*)&wv[8]  = *(const float4*)&sW[c * 144 + k * 16 + 8];
                *(float4*)&wv[12] = *(const float4*)&sW[c * 144 + k * 16 + 12];
#pragma unroll
                for (int j = 0; j < 16; ++j) acc[j] += vv * wv[j];
            }
        }
    }
#pragma unroll
    for (int j = 0; j < 16; ++j)
        out[((size_t)(n * 256 + oc0 + j) * 16 + row) * 16 + col] = acc[j] + bias[oc0 + j];
}

// per-(clip,channel) BN stats
__global__ void k_bn_stats(const float* __restrict__ buf, const float* __restrict__ g,
                           const float* __restrict__ be, float* __restrict__ scale,
                           float* __restrict__ shift, int C, int HW) {
    int c = blockIdx.x, ch = blockIdx.y, tid = threadIdx.x;
    float s = 0.f, s2 = 0.f;
    for (int b = 0; b < 4; ++b) {
        const float* p = buf + ((size_t)(c * 4 + b) * C + ch) * HW;
        for (int i = tid; i < HW; i += 256) { float v = p[i]; s += v; s2 += v * v; }
    }
    __shared__ float rs[256], rq[256];
    rs[tid] = s; rq[tid] = s2; __syncthreads();
    for (int k = 128; k > 0; k >>= 1) {
        if (tid < k) { rs[tid] += rs[tid + k]; rq[tid] += rq[tid + k]; }
        __syncthreads();
    }
    if (tid == 0) {
        float inv = 1.f / (float)(4 * HW);
        float m = rs[0] * inv, var = rq[0] * inv - m * m;
        float sc = g[ch] * rsqrtf(var + 1e-5f);
        scale[c * C + ch] = sc;
        shift[c * C + ch] = be[ch] - m * sc;
    }
}

__global__ void k_bn_apply_pool(const float* __restrict__ in, const float* __restrict__ scale,
                                const float* __restrict__ shift, float* __restrict__ out,
                                int C, int H, int W) {
    int OH = H >> 1, OW = W >> 1;
    size_t idx = (size_t)blockIdx.x * 256 + threadIdx.x;
    int ow = (int)(idx % OW);
    size_t r = idx / OW;
    int oh = (int)(r % OH); r /= OH;
    int ch = (int)(r % C);
    int n = (int)(r / C);
    int c = n >> 2;
    float sc = scale[c * C + ch], sh = shift[c * C + ch];
    const float* p = in + (((size_t)n * C + ch) * H + 2 * oh) * W + 2 * ow;
    float m = 0.f;
    m = fmaxf(m, p[0] * sc + sh);
    m = fmaxf(m, p[1] * sc + sh);
    m = fmaxf(m, p[W] * sc + sh);
    m = fmaxf(m, p[W + 1] * sc + sh);
    out[idx] = m;
}

// ---- post-conv3 chain ----
__global__ void k_bn_apply_avgpool4(const float* __restrict__ in, const float* __restrict__ scale,
                                    const float* __restrict__ shift, float* __restrict__ out) {
    size_t idx = (size_t)blockIdx.x * 256 + threadIdx.x;  // 262,144
    int j = (int)(idx & 3), i = (int)(idx >> 2) & 3;
    int ch = (int)(idx >> 4) & 255, n = (int)(idx >> 12);
    int c = n >> 2;
    float sc = scale[c * 256 + ch], sh = shift[c * 256 + ch];
    const float* p = in + (((size_t)n * 256 + ch) * 16 + i * 4) * 16 + j * 4;
    float s = 0.f;
#pragma unroll
    for (int r = 0; r < 4; ++r)
#pragma unroll
        for (int q = 0; q < 4; ++q) s += fmaxf(p[r * 16 + q] * sc + sh, 0.f);
    out[idx] = s * (1.f / 16.f);
}

__global__ void k_tconv(const float* __restrict__ x3p, const float* __restrict__ tw,
                        const float* __restrict__ tb, float* __restrict__ y4) {
    size_t idx = (size_t)blockIdx.x * 256 + threadIdx.x;  // 262,144
    int p = (int)(idx & 15), o = (int)(idx >> 4) & 255, n = (int)(idx >> 12);
    const float* xr = x3p + (size_t)n * 4096 + p;
    float a = tb[o];
    for (int i = 0; i < 256; ++i) a += xr[i * 16] * tw[((size_t)o * 256 + i) * 3 + 1];
    y4[idx] = a;
}

__global__ void k_bn_apply(const float* __restrict__ in, const float* __restrict__ scale,
                           const float* __restrict__ shift, float* __restrict__ out) {
    size_t idx = (size_t)blockIdx.x * 256 + threadIdx.x;  // 262,144
    int ch = (int)(idx >> 4) & 255, n = (int)(idx >> 12);
    int c = n >> 2;
    float sc = scale[c * 256 + ch], sh = shift[c * 256 + ch];
    out[idx] = fmaxf(in[idx] * sc + sh, 0.f);
}

__global__ void k_proj(const float* __restrict__ x4, const float* __restrict__ pw,
                       const float* __restrict__ pb, float* __restrict__ feat) {
    int d0 = blockIdx.x * 8;
    int ro = threadIdx.x >> 2;
    int cp = threadIdx.x & 3;
    int c0 = d0 + cp * 2, c1 = c0 + 1;
    int n = (ro & 15) * 4 + (ro >> 4);
    const float* x = x4 + (size_t)n * 4096;
    const float* w0 = pw + (size_t)c0 * 4096;
    const float* w1 = pw + (size_t)c1 * 4096;
    float a0 = pb[c0], a1 = pb[c1];
    for (int k = 0; k < 4096; ++k) { float f = x[k]; a0 += f * w0[k]; a1 += f * w1[k]; }
    feat[(size_t)ro * 512 + c0] = a0;
    feat[(size_t)ro * 512 + c1] = a1;
}

// VQ argmin; min distance -> commitArr[row] (deterministic)
__global__ void k_vq(const float* __restrict__ feat, const float* __restrict__ cb,
                     float* __restrict__ quant, float* __restrict__ commitArr) {
    int row = blockIdx.x, tid = threadIdx.x;
    __shared__ float f[512];
    for (int k = tid; k < 512; k += 256) f[k] = feat[(size_t)row * 512 + k];
    __syncthreads();
    float best = 3.4e38f; int bidx = 0;
    for (int j = tid; j < 1024; j += 256) {
        const float* c = cb + (size_t)j * 512;
        float d2 = 0.f;
        for (int k = 0; k < 512; ++k) { float t = f[k] - c[k]; d2 += t * t; }
        if (d2 < best) { best = d2; bidx = j; }
    }
    __shared__ float rd[256]; __shared__ int ri[256];
    rd[tid] = best; ri[tid] = bidx; __syncthreads();
    for (int k = 128; k > 0; k >>= 1) {
        if (tid < k) {
            float od = rd[tid + k]; int oi = ri[tid + k];
            if (od < rd[tid] || (od == rd[tid] && oi < ri[tid])) { rd[tid] = od; ri[tid] = oi; }
        }
        __syncthreads();
    }
    __shared__ int wsel;
    if (tid == 0) { wsel = ri[0]; commitArr[row] = rd[0]; }
    __syncthreads();
    const float* c = cb + (size_t)wsel * 512;
    for (int k = tid; k < 512; k += 256) quant[(size_t)row * 512 + k] = c[k];
}

// gi = X @ w_ih.T + b_ih, rows (b, t) t=0..14; X and gi rows at stride-16 (b*16+t)
__global__ void k_gru_gi(const float* __restrict__ x, const float* __restrict__ wih,
                         const float* __restrict__ bih, float* __restrict__ gi) {
    int r = blockIdx.x;  // 0..59
    int b = r / 15, t = r % 15;
    const float* xr = x + ((size_t)(b * 16 + t)) * 512;
    __shared__ float xsRow[512];
    for (int k = threadIdx.x; k < 512; k += 256) xsRow[k] = xr[k];
    __syncthreads();
    const float4* xp = (const float4*)xsRow;
    for (int d = threadIdx.x; d < 1536; d += 256) {
        const float4* wr = (const float4*)(wih + (size_t)d * 512);
        float a0 = 0.f, a1 = 0.f, a2 = 0.f, a3 = 0.f;
        for (int i = 0; i < 128; i += 4) {
            float4 w0 = wr[i], w1 = wr[i + 1], w2 = wr[i + 2], w3 = wr[i + 3];
            float4 x0 = xp[i], x1 = xp[i + 1], x2 = xp[i + 2], x3 = xp[i + 3];
            a0 += w0.x * x0.x + w0.y * x0.y + w0.z * x0.z + w0.w * x0.w;
            a1 += w1.x * x1.x + w1.y * x1.y + w1.z * x1.z + w1.w * x1.w;
            a2 += w2.x * x2.x + w2.y * x2.y + w2.z * x2.z + w2.w * x2.w;
            a3 += w3.x * x3.x + w3.y * x3.y + w3.z * x3.z + w3.w * x3.w;
        }
        gi[((size_t)(b * 16 + t)) * 1536 + d] = (a0 + a1) + (a2 + a3) + bih[d];
    }
}

// One GRU step: grid 128 (4 h-dims each), wave = one h-dim, float4 rows.
__global__ void k_gru_step2(const float* __restrict__ gi, const float* __restrict__ whh,
                            const float* __restrict__ bhh, float* __restrict__ hseq, int t) {
    int wv = threadIdx.x >> 6, lane = threadIdx.x & 63;
    int d = blockIdx.x * 4 + wv;
    const float4* w0p = (const float4*)(whh + (size_t)d * 512);
    const float4* w1p = (const float4*)(whh + (size_t)(512 + d) * 512);
    const float4* w2p = (const float4*)(whh + (size_t)(1024 + d) * 512);
    float4 w0a = w0p[lane * 2], w0b = w0p[lane * 2 + 1];
    float4 w1a = w1p[lane * 2], w1b = w1p[lane * 2 + 1];
    float4 w2a = w2p[lane * 2], w2b = w2p[lane * 2 + 1];
    float bh0 = bhh[d], bh1 = bhh[512 + d], bh2 = bhh[1024 + d];
    for (int b = 0; b < 4; ++b) {
        float4 ha = make_float4(0, 0, 0, 0), hb = ha;
        float hpd = 0.f;
        if (t > 0) {
            const float4* hp = (const float4*)(hseq + (size_t)(b * 16 + t - 1) * 512);
            ha = hp[lane * 2]; hb = hp[lane * 2 + 1];
            hpd = hseq[(size_t)(b * 16 + t - 1) * 512 + d];
        }
        float s0 = w0a.x * ha.x + w0a.y * ha.y + w0a.z * ha.z + w0a.w * ha.w
                 + w0b.x * hb.x + w0b.y * hb.y + w0b.z * hb.z + w0b.w * hb.w;
        float s1 = w1a.x * ha.x + w1a.y * ha.y + w1a.z * ha.z + w1a.w * ha.w
                 + w1b.x * hb.x + w1b.y * hb.y + w1b.z * hb.z + w1b.w * hb.w;
        float s2 = w2a.x * ha.x + w2a.y * ha.y + w2a.z * ha.z + w2a.w * ha.w
                 + w2b.x * hb.x + w2b.y * hb.y + w2b.z * hb.z + w2b.w * hb.w;
#pragma unroll
        for (int m = 1; m < 64; m <<= 1) {
            s0 += __shfl_xor(s0, m);
            s1 += __shfl_xor(s1, m);
            s2 += __shfl_xor(s2, m);
        }
        const float* gr = gi + (size_t)(b * 16 + t) * 1536;
        float rr = 1.f / (1.f + expf(-(gr[d] + s0 + bh0)));
        float zz = 1.f / (1.f + expf(-(gr[512 + d] + s1 + bh1)));
        float nn = tanhf(gr[1024 + d] + rr * (s2 + bh2));
        if (lane == 0)
            hseq[(size_t)(b * 16 + t) * 512 + d] = (1.f - zz) * nn + zz * hpd;
    }
}

// ctx loss partials -> ctxArr[block] (deterministic)
__global__ void k_ctx_loss(const float* __restrict__ h2, const float* __restrict__ feat,
                           float* __restrict__ ctxArr) {
    int tid = threadIdx.x;
    size_t idx = (size_t)blockIdx.x * 256 + tid;  // 30720
    int d = (int)(idx & 511);
    int rt = (int)(idx >> 9);
    int t = rt % 15, b = rt / 15;
    float diff = h2[(size_t)(b * 16 + t) * 512 + d] - feat[(size_t)(b * 16 + t + 1) * 512 + d];
    float v = diff * diff;
#pragma unroll
    for (int m = 1; m < 64; m <<= 1) v += __shfl_xor(v, m);
    __shared__ float ws[4];
    if ((tid & 63) == 0) ws[tid >> 6] = v;
    __syncthreads();
    if (tid == 0) ctxArr[blockIdx.x] = ((ws[0] + ws[1]) + (ws[2] + ws[3]));
}

__global__ void k_word_vq(const float* __restrict__ quant, const float* __restrict__ wcb,
                          float* __restrict__ wemb, float* __restrict__ out_widx) {
    int row = blockIdx.x;  // b*8+wi
    int b = row >> 3, wi = row & 7;
    int tid = threadIdx.x;
    __shared__ float f[512];
    for (int k = tid; k < 512; k += 256)
        f[k] = 0.5f * (quant[(size_t)(b * 16 + 2 * wi) * 512 + k] +
                       quant[(size_t)(b * 16 + 2 * wi + 1) * 512 + k]);
    __syncthreads();
    const float* cp = wcb + (size_t)tid * 512;
    float d2 = 0.f;
    for (int k = 0; k < 512; ++k) { float t = f[k] - cp[k]; d2 += t * t; }
    __shared__ float rd[256]; __shared__ int ri[256];
    rd[tid] = d2; ri[tid] = tid; __syncthreads();
    for (int k = 128; k > 0; k >>= 1) {
        if (tid < k) {
            float od = rd[tid + k]; int oi = ri[tid + k];
            if (od < rd[tid] || (od == rd[tid] && oi < ri[tid])) { rd[tid] = od; ri[tid] = oi; }
        }
        __syncthreads();
    }
    __shared__ int wsel;
    if (tid == 0) { wsel = ri[0]; out_widx[row] = (float)ri[0]; }
    __syncthreads();
    const float* cb = wcb + (size_t)wsel * 512;
    for (int k = tid; k < 512; k += 256) wemb[(size_t)row * 512 + k] = cb[k];
}

// alignment partials -> alignArr[row] (deterministic)
__global__ void k_align(const float* __restrict__ wemb, const float* __restrict__ aw,
                        const float* __restrict__ ab, float* __restrict__ alignArr) {
    int row = blockIdx.x, tid = threadIdx.x;
    __shared__ float e[512];
    for (int k = tid; k < 512; k += 256) e[k] = wemb[(size_t)row * 512 + k];
    __syncthreads();
    float local = 0.f;
    for (int d = tid; d < 512; d += 256) {
        const float* wr = aw + (size_t)d * 512;
        float a = ab[d] - e[d];
        for (int k = 0; k < 512; ++k) a += e[k] * wr[k];
        local += a * a;
    }
    __shared__ float rs[256];
    rs[tid] = local; __syncthreads();
    for (int k = 128; k > 0; k >>= 1) { if (tid < k) rs[tid] += rs[tid + k]; __syncthreads(); }
    if (tid == 0) alignArr[row] = rs[0];
}

__global__ void k_ctx(const float* __restrict__ wemb, float* __restrict__ ctx) {
    int e = blockIdx.x * 256 + threadIdx.x;  // 2048
    int b = e >> 9, d = e & 511;
    float s = 0.f;
#pragma unroll
    for (int wi = 0; wi < 8; ++wi) s += wemb[(size_t)(b * 8 + wi) * 512 + d];
    ctx[e] = s * 0.125f;
}

// small-M (M=4) GEMV: C[4,N] = A[4,K] @ B[N,K]^T + bias, optional relu.
__global__ void k_smallM(const float* __restrict__ A, const float* __restrict__ B,
                         const float* __restrict__ bias, float* __restrict__ C,
                         int N, int K, int relu) {
    __shared__ float xs[4096];
    int tid = threadIdx.x;
    for (int e = tid; e < 4 * K; e += 256) xs[e] = A[e];
    __syncthreads();
    int r = tid >> 4, kt = tid & 15;
    int n = blockIdx.x * 16 + r;
    float acc[4] = {0, 0, 0, 0};
    if (n < N) {
        int iters = K >> 6;
        for (int i = 0; i < iters; ++i) {
            int k = i * 64 + kt * 4;
            float4 w = *(const float4*)&B[(size_t)n * K + k];
#pragma unroll
            for (int b = 0; b < 4; ++b) {
                float4 x = *(const float4*)&xs[b * K + k];
                acc[b] += w.x * x.x + w.y * x.y + w.z * x.z + w.w * x.w;
            }
        }
    }
#pragma unroll
    for (int b = 0; b < 4; ++b) {
#pragma unroll
        for (int m = 1; m < 16; m <<= 1) acc[b] += __shfl_xor(acc[b], m);
    }
    if (kt == 0 && n < N) {
#pragma unroll
        for (int b = 0; b < 4; ++b) {
            float v = acc[b] + bias[n];
            if (relu) v = fmaxf(v, 0.f);
            C[(size_t)b * N + n] = v;
        }
    }
}

// log-softmax CE + deterministic fixed-order sum of all loss partials
__global__ void k_final(const float* __restrict__ logits, const int* __restrict__ tokens,
                        const float* __restrict__ commitArr, const float* __restrict__ ctxArr,
                        const float* __restrict__ alignArr, float* __restrict__ out_total) {
    int tid = threadIdx.x;
    __shared__ float rs[256];
    __shared__ float sM;
    float tr = 0.f;
    for (int b = 0; b < 4; ++b) {
        const float* lg = logits + (size_t)b * 3000;
        float m = -1e30f;
        for (int d = tid; d < 3000; d += 256) m = fmaxf(m, lg[d]);
        rs[tid] = m; __syncthreads();
        for (int k = 128; k > 0; k >>= 1) { if (tid < k) rs[tid] = fmaxf(rs[tid], rs[tid + k]); __syncthreads(); }
        if (tid == 0) sM = rs[0];
        __syncthreads();
        float M = sM;
        float s = 0.f;
        for (int d = tid; d < 3000; d += 256) s += expf(lg[d] - M);
        rs[tid] = s; __syncthreads();
        for (int k = 128; k > 0; k >>= 1) { if (tid < k) rs[tid] += rs[tid + k]; __syncthreads(); }
        if (tid == 0) {
            int t0 = tokens[b * 10];
            tr += -(lg[t0] - M - logf(rs[0]));
        }
        __syncthreads();
    }
    if (tid == 0) {
        float c0 = 0.f;
        for (int i = 0; i < 64; ++i) c0 += commitArr[i];
        float c1 = 0.f;
        for (int i = 0; i < 120; ++i) c1 += ctxArr[i];
        float c2 = 0.f;
        for (int i = 0; i < 32; ++i) c2 += alignArr[i];
        float total = 1.25f * c0 * (1.f / 32768.f)
                    + 0.1f  * c1 * (1.f / 30720.f)
                    + 0.1f  * c2 * (1.f / 16384.f)
                    + tr;
        *out_total = total;
    }
}

extern "C" void kernel_launch(void* const* d_in, const int* in_sizes, int n_in,
                              void* d_out, int out_size, void* d_ws, size_t ws_size,
                              hipStream_t stream) {
    (void)in_sizes; (void)n_in; (void)out_size; (void)ws_size;
    const float* videos   = (const float*)d_in[0];
    const float* conv1_w  = (const float*)d_in[1];
    const float* conv1_b  = (const float*)d_in[2];
    const float* bn1_g    = (const float*)d_in[3];
    const float* bn1_b    = (const float*)d_in[4];
    const float* conv2_w  = (const float*)d_in[5];
    const float* conv2_b  = (const float*)d_in[6];
    const float* bn2_g    = (const float*)d_in[7];
    const float* bn2_b    = (const float*)d_in[8];
    const float* conv3_w  = (const float*)d_in[9];
    const float* conv3_b  = (const float*)d_in[10];
    const float* bn3_g    = (const float*)d_in[11];
    const float* bn3_b    = (const float*)d_in[12];
    const float* tconv_w  = (const float*)d_in[13];
    const float* tconv_b  = (const float*)d_in[14];
    const float* bn4_g    = (const float*)d_in[15];
    const float* bn4_b    = (const float*)d_in[16];
    const float* proj_w   = (const float*)d_in[17];
    const float* proj_b   = (const float*)d_in[18];
    const float* codebook = (const float*)d_in[19];
    const float* word_cb  = (const float*)d_in[20];
    const float* align_w  = (const float*)d_in[21];
    const float* align_b  = (const float*)d_in[22];
    const float* gru_wih0 = (const float*)d_in[23];
    const float* gru_whh0 = (const float*)d_in[24];
    const float* gru_bih0 = (const float*)d_in[25];
    const float* gru_bhh0 = (const float*)d_in[26];
    const float* gru_wih1 = (const float*)d_in[27];
    const float* gru_whh1 = (const float*)d_in[28];
    const float* gru_bih1 = (const float*)d_in[29];
    const float* gru_bhh1 = (const float*)d_in[30];
    const float* dec1_w   = (const float*)d_in[31];
    const float* dec1_b   = (const float*)d_in[32];
    const float* dec2_w   = (const float*)d_in[33];
    const float* dec2_b   = (const float*)d_in[34];
    const float* dec3_w   = (const float*)d_in[35];
    const float* dec3_b   = (const float*)d_in[36];
    const int*   tokens   = (const int*)d_in[37];

    float* wsf    = (float*)d_ws;
    float* out    = (float*)d_out;
    float* x1p    = wsf + OFF_X1P;
    float* x2p    = wsf + OFF_X2P;
    float* y2     = wsf + OFF_Y2;
    float* y3     = wsf + OFF_Y3;
    float* x3p    = wsf + OFF_X3P;
    float* y4     = wsf + OFF_Y4;
    float* x4     = wsf + OFF_X4;
    float* feat   = wsf + OFF_FEAT;
    float* quant  = wsf + OFF_QUANT;
    float* gi1    = wsf + OFF_GI1;
    float* gi2    = wsf + OFF_GI2;
    float* h1     = wsf + OFF_H1;
    float* h2     = wsf + OFF_H2;
    float* wemb   = wsf + OFF_WEMB;
    float* ctx    = wsf + OFF_CTX;
    float* hh1    = wsf + OFF_HH1;
    float* hh2    = wsf + OFF_HH2;
    float* logit  = wsf + OFF_LOG;
    float* sc     = wsf + OFF_SC;
    float* sh     = wsf + OFF_SH;
    float* accP   = wsf + OFF_ACCP;
    float* commitA= wsf + OFF_COMMIT;
    float* ctxA   = wsf + OFF_CTXA;
    float* alignA = wsf + OFF_ALIGNA;

    // conv1 + bn1 + pool
    k_conv1_stats2<<<dim3(4, 64), 256, 0, stream>>>(videos, conv1_w, conv1_b, accP);
    k_conv1_fin<<<4, 256, 0, stream>>>(accP, bn1_g, bn1_b, sc, sh);
    k_conv1_apply2<<<dim3(4, 64), 256, 0, stream>>>(videos, conv1_w, conv1_b, sc, sh, x1p);
    // conv2 + bn2 + pool
    k_conv2<<<dim3(8, 2, 64), 256, 0, stream>>>(x1p, conv2_w, conv2_b, y2);
    k_bn_stats<<<dim3(16, 128), 256, 0, stream>>>(y2, bn2_g, bn2_b, sc, sh, 128, 1024);
    k_bn_apply_pool<<<8192, 256, 0, stream>>>(y2, sc, sh, x2p, 128, 32, 32);
    // conv3 + bn3 + chain
    k_conv3k<<<dim3(16, 64), 256, 0, stream>>>(x2p, conv3_w, conv3_b, y3);
    k_bn_stats<<<dim3(16, 256), 256, 0, stream>>>(y3, bn3_g, bn3_b, sc, sh, 256, 256);
    k_bn_apply_avgpool4<<<1024, 256, 0, stream>>>(y3, sc, sh, x3p);
    k_tconv<<<1024, 256, 0, stream>>>(x3p, tconv_w, tconv_b, y4);
    k_bn_stats<<<dim3(16, 256), 256, 0, stream>>>(y4, bn4_g, bn4_b, sc, sh, 256, 16);
    k_bn_apply<<<1024, 256, 0, stream>>>(y4, sc, sh, x4);
    k_proj<<<64, 256, 0, stream>>>(x4, proj_w, proj_b, feat);
    k_vq<<<64, 256, 0, stream>>>(feat, codebook, quant, commitA);
    // GRU layer 1
    k_gru_gi<<<60, 256, 0, stream>>>(quant, gru_wih0, gru_bih0, gi1);
    for (int t = 0; t < 15; ++t)
        k_gru_step2<<<128, 256, 0, stream>>>(gi1, gru_whh0, gru_bhh0, h1, t);
    // GRU layer 2
    k_gru_gi<<<60, 256, 0, stream>>>(h1, gru_wih1, gru_bih1, gi2);
    for (int t = 0; t < 15; ++t)
        k_gru_step2<<<128, 256, 0, stream>>>(gi2, gru_whh1, gru_bhh1, h2, t);
    k_ctx_loss<<<120, 256, 0, stream>>>(h2, feat, ctxA);
    // word VQ + alignment
    k_word_vq<<<32, 256, 0, stream>>>(quant, word_cb, wemb, out);
    k_align<<<32, 256, 0, stream>>>(wemb, align_w, align_b, alignA);
    // decoder
    k_ctx<<<8, 256, 0, stream>>>(wemb, ctx);
    k_smallM<<<32, 256, 0, stream>>>(ctx, dec1_w, dec1_b, hh1, 512, 512, 1);
    k_smallM<<<64, 256, 0, stream>>>(hh1, dec2_w, dec2_b, hh2, 1024, 512, 1);
    k_smallM<<<188, 256, 0, stream>>>(hh2, dec3_w, dec3_b, logit, 3000, 1024, 0);
    k_final<<<1, 256, 0, stream>>>(logit, tokens, commitA, ctxA, alignA, out + 32);
}

// Round 8
// 1318.745 us; speedup vs baseline: 2.2522x; 1.1525x over previous
//
#include <hip/hip_runtime.h>

// ============================================================================
// SignLLM forward, fp32. B=4, T=32 -> nc=16 clips, D=512.
// Output: d_out[0..31] = widx (4,8) as float, d_out[32] = total loss.
// R7: R6 kernels with ONE fix — k_proj_fin now applies the x4(clip-major
// n=c*4+b) -> feat(batch-major ro=b*16+c) row permutation that the old
// k_proj had and the R6 split-K rewrite dropped (root cause of R6's widx
// scramble). All reductions remain atomic-free (deterministic).
// ============================================================================

// ---- workspace layout (float offsets), peak ~12.60M floats = 50.4 MB ----
static const size_t OFF_X1P  = 0;         // (64,64,32,32)  4,194,304  [dead after conv2]
static const size_t OFF_Y2   = 4194304;   // (64,128,32,32) 8,388,608  -> ends 12,582,912
static const size_t OFF_X2P  = 0;         // (64,128,16,16) 2,097,152  [x1p dead]
static const size_t OFF_Y3   = 4194304;   // (64,256,16,16) 4,194,304  [y2 dead]
// tail block in [2097152, 4194304): x1p dead by the time these are written
static const size_t OFF_X3P  = 2097152;   // 262,144
static const size_t OFF_Y4   = 2359296;   // 262,144
static const size_t OFF_X4   = 2621440;   // 262,144
static const size_t OFF_FEAT = 2883584;   // (64,512) 32,768
static const size_t OFF_QUANT= 2916352;   // 32,768
static const size_t OFF_GI1  = 2949120;   // (64,1536) 98,304 (rows b*16+t)
static const size_t OFF_GI2  = 3047424;   // 98,304
static const size_t OFF_H1   = 3145728;   // (64,512) rows b*16+t
static const size_t OFF_H2   = 3178496;   // 32,768
static const size_t OFF_WEMB = 3211264;   // (32,512) 16,384
static const size_t OFF_CTX  = 3227648;   // 2,048
static const size_t OFF_HH1  = 3229696;   // 2,048
static const size_t OFF_HH2  = 3231744;   // 4,096
static const size_t OFF_LOG  = 3235840;   // 12,000 -> ends 3,247,840
static const size_t OFF_PP   = 3247840;   // proj partials (8,64,512) 262,144 -> ends 3,509,984
// long-lived block PAST y2's end (12,582,912):
static const size_t OFF_SC    = 12582912; // 4,096
static const size_t OFF_SH    = 12587008; // 4,096
static const size_t OFF_ACCP  = 12591104; // 8,192: conv1 partials (sum, then sq)
static const size_t OFF_COMMIT= 12599296; // 64
static const size_t OFF_CTXA  = 12599360; // 120
static const size_t OFF_ALIGNA= 12599480; // 32 -> ends 12,599,512

// ============================================================================
// conv1 (IC=3, 64x64, pad 1, mid temporal slice). Plane in LDS, 6x6 patch in
// regs, 16 oc/block. grid (4 ocg, 64 n), 256 thr; thread = 4x4 positions.
// Stats: deterministic — per-block partial per (c,oc) -> accP[(c*64+oc)*4+b].
// ============================================================================
__global__ __launch_bounds__(256, 2) void k_conv1_stats2(
        const float* __restrict__ videos, const float* __restrict__ w1,
        const float* __restrict__ b1, float* __restrict__ accP) {
    __shared__ float sP[3 * 66 * 66];
    __shared__ float wsm[3 * 9 * 16];
    __shared__ float sRed[4][4], qRed[4][4];  // [wave][j]
    int oc0 = blockIdx.x * 16, n = blockIdx.y;
    int c = n >> 2, b = n & 3;
    int tid = threadIdx.x;
    for (int e = tid; e < 3 * 66 * 66; e += 256) {
        int ic = e / 4356, rem = e % 4356;
        int r = rem / 66, col = rem % 66;
        float v = 0.f;
        if (r >= 1 && r <= 64 && col >= 1 && col <= 64)
            v = videos[((size_t)(b * 3 + ic) * 32 + 2 * c) * 4096 + (r - 1) * 64 + (col - 1)];
        sP[e] = v;
    }
    for (int e = tid; e < 432; e += 256) {
        int ic = e / 144, rem = e % 144, k = rem / 16, j = rem % 16;
        wsm[e] = w1[((size_t)((oc0 + j) * 3 + ic) * 3 + 1) * 9 + k];
    }
    __syncthreads();
    int ph0 = (tid >> 4) * 4, pw0 = (tid & 15) * 4;
    int lane = tid & 63, wave = tid >> 6;
    for (int cc = 0; cc < 4; ++cc) {
        float acc[16][4];
#pragma unroll
        for (int p = 0; p < 16; ++p)
#pragma unroll
            for (int j = 0; j < 4; ++j) acc[p][j] = 0.f;
#pragma unroll
        for (int ic = 0; ic < 3; ++ic) {
            float patch[36];
#pragma unroll
            for (int r = 0; r < 6; ++r)
#pragma unroll
                for (int q = 0; q < 6; ++q)
                    patch[r * 6 + q] = sP[ic * 4356 + (ph0 + r) * 66 + pw0 + q];
#pragma unroll
            for (int k = 0; k < 9; ++k) {
                int kr = k / 3, kc = k % 3;
                float4 wf = *(const float4*)&wsm[(ic * 9 + k) * 16 + cc * 4];
#pragma unroll
                for (int p = 0; p < 16; ++p) {
                    int pr = p >> 2, pc = p & 3;
                    float vv = patch[(pr + kr) * 6 + pc + kc];
                    acc[p][0] += vv * wf.x; acc[p][1] += vv * wf.y;
                    acc[p][2] += vv * wf.z; acc[p][3] += vv * wf.w;
                }
            }
        }
        float s_[4] = {0, 0, 0, 0}, q_[4] = {0, 0, 0, 0};
#pragma unroll
        for (int j = 0; j < 4; ++j) {
            float bj = b1[oc0 + cc * 4 + j];
#pragma unroll
            for (int p = 0; p < 16; ++p) {
                float a = acc[p][j] + bj;
                s_[j] += a; q_[j] += a * a;
            }
        }
#pragma unroll
        for (int j = 0; j < 4; ++j) {
#pragma unroll
            for (int m = 1; m < 64; m <<= 1) {
                s_[j] += __shfl_xor(s_[j], m);
                q_[j] += __shfl_xor(q_[j], m);
            }
            if (lane == 0) { sRed[wave][j] = s_[j]; qRed[wave][j] = q_[j]; }
        }
        __syncthreads();
        if (tid < 4) {  // j = tid
            float s = ((sRed[0][tid] + sRed[1][tid]) + (sRed[2][tid] + sRed[3][tid]));
            float q = ((qRed[0][tid] + qRed[1][tid]) + (qRed[2][tid] + qRed[3][tid]));
            int oc = oc0 + cc * 4 + tid;
            accP[((size_t)(c * 64 + oc)) * 4 + b] = s;
            accP[4096 + ((size_t)(c * 64 + oc)) * 4 + b] = q;
        }
        __syncthreads();
    }
}

__global__ void k_conv1_fin(const float* __restrict__ accP, const float* __restrict__ g1,
                            const float* __restrict__ be1, float* __restrict__ sc,
                            float* __restrict__ sh) {
    int e = blockIdx.x * 256 + threadIdx.x;
    if (e >= 1024) return;
    int oc = e & 63;
    const float* ps = accP + (size_t)e * 4;
    const float* pq = accP + 4096 + (size_t)e * 4;
    float s = ((ps[0] + ps[1]) + (ps[2] + ps[3]));
    float q = ((pq[0] + pq[1]) + (pq[2] + pq[3]));
    float m = s * (1.f / 16384.f);
    float var = q * (1.f / 16384.f) - m * m;
    float sf = g1[oc] * rsqrtf(var + 1e-5f);
    sc[e] = sf;
    sh[e] = be1[oc] - m * sf;
}

__global__ __launch_bounds__(256, 2) void k_conv1_apply2(
        const float* __restrict__ videos, const float* __restrict__ w1,
        const float* __restrict__ b1, const float* __restrict__ sc,
        const float* __restrict__ sh, float* __restrict__ x1p) {
    __shared__ float sP[3 * 66 * 66];
    __shared__ float wsm[3 * 9 * 16];
    int oc0 = blockIdx.x * 16, n = blockIdx.y;
    int c = n >> 2, b = n & 3;
    int tid = threadIdx.x;
    for (int e = tid; e < 3 * 66 * 66; e += 256) {
        int ic = e / 4356, rem = e % 4356;
        int r = rem / 66, col = rem % 66;
        float v = 0.f;
        if (r >= 1 && r <= 64 && col >= 1 && col <= 64)
            v = videos[((size_t)(b * 3 + ic) * 32 + 2 * c) * 4096 + (r - 1) * 64 + (col - 1)];
        sP[e] = v;
    }
    for (int e = tid; e < 432; e += 256) {
        int ic = e / 144, rem = e % 144, k = rem / 16, j = rem % 16;
        wsm[e] = w1[((size_t)((oc0 + j) * 3 + ic) * 3 + 1) * 9 + k];
    }
    __syncthreads();
    int ph0 = (tid >> 4) * 4, pw0 = (tid & 15) * 4;
    for (int cc = 0; cc < 4; ++cc) {
        float acc[16][4];
#pragma unroll
        for (int p = 0; p < 16; ++p)
#pragma unroll
            for (int j = 0; j < 4; ++j) acc[p][j] = 0.f;
#pragma unroll
        for (int ic = 0; ic < 3; ++ic) {
            float patch[36];
#pragma unroll
            for (int r = 0; r < 6; ++r)
#pragma unroll
                for (int q = 0; q < 6; ++q)
                    patch[r * 6 + q] = sP[ic * 4356 + (ph0 + r) * 66 + pw0 + q];
#pragma unroll
            for (int k = 0; k < 9; ++k) {
                int kr = k / 3, kc = k % 3;
                float4 wf = *(const float4*)&wsm[(ic * 9 + k) * 16 + cc * 4];
#pragma unroll
                for (int p = 0; p < 16; ++p) {
                    int pr = p >> 2, pc = p & 3;
                    float vv = patch[(pr + kr) * 6 + pc + kc];
                    acc[p][0] += vv * wf.x; acc[p][1] += vv * wf.y;
                    acc[p][2] += vv * wf.z; acc[p][3] += vv * wf.w;
                }
            }
        }
#pragma unroll
        for (int j = 0; j < 4; ++j) {
            int oc = oc0 + cc * 4 + j;
            float bj = b1[oc];
            float scj = sc[c * 64 + oc], shj = sh[c * 64 + oc];
#pragma unroll
            for (int pr2 = 0; pr2 < 2; ++pr2)
#pragma unroll
                for (int pc2 = 0; pc2 < 2; ++pc2) {
                    float m = -1e30f;
#pragma unroll
                    for (int dr = 0; dr < 2; ++dr)
#pragma unroll
                        for (int dc = 0; dc < 2; ++dc) {
                            int p = (pr2 * 2 + dr) * 4 + pc2 * 2 + dc;
                            float v = (acc[p][j] + bj) * scj + shj;
                            m = fmaxf(m, v);
                        }
                    int prow = (tid >> 4) * 2 + pr2, pcol = (tid & 15) * 2 + pc2;
                    x1p[((size_t)n * 64 + oc) * 1024 + prow * 32 + pcol] = fmaxf(m, 0.f);
                }
        }
    }
}

// ============================================================================
// conv2: IC=64, 32x32, OC=128. Block = 1 clip x 8-row slab x 16 oc.
// grid (8 ocg, 4 slab, 64 n) = 2048 blocks. Thread = 4 oc x (2x2 px).
// Weight read: ONE wave-uniform b128 per k. LDS stride 35.
// ============================================================================
__global__ __launch_bounds__(256) void k_conv2(
        const float* __restrict__ in, const float* __restrict__ wt,
        const float* __restrict__ bias, float* __restrict__ out) {
    __shared__ float sIn[8 * 10 * 35];   // 2800 floats
    __shared__ float sW[8 * 144];        // 1152 floats
    int oc0 = blockIdx.x * 16, r0 = blockIdx.y * 8, n = blockIdx.z;
    int tid = threadIdx.x;
    int ocq = tid >> 6, pxq = tid & 63;
    int prow = pxq >> 4, pcol = pxq & 15;   // px rows r0+2prow+dr, cols 2pcol+dc
    float acc[4][4];
#pragma unroll
    for (int j = 0; j < 4; ++j)
#pragma unroll
        for (int p = 0; p < 4; ++p) acc[j][p] = 0.f;

    for (int ic0 = 0; ic0 < 64; ic0 += 8) {
        __syncthreads();
        for (int e = tid; e < 2800; e += 256) {
            int ch = e / 350, rem = e % 350;
            int r = rem / 35, col = rem % 35;
            int gr = r0 - 1 + r, gc = col - 1;
            float v = 0.f;
            if (gr >= 0 && gr < 32 && gc >= 0 && gc < 32)
                v = in[((size_t)(n * 64 + ic0 + ch) * 32 + gr) * 32 + gc];
            sIn[e] = v;
        }
        for (int e = tid; e < 1152; e += 256) {
            int c = e / 144, r1 = e % 144, k = r1 / 16, j = r1 % 16;
            sW[e] = wt[((size_t)(oc0 + j) * 64 + ic0 + c) * 27 + 9 + k];
        }
        __syncthreads();
        for (int c = 0; c < 8; ++c) {
            const float* base = &sIn[c * 350 + (2 * prow) * 35 + 2 * pcol];
            float patch[4][4];
#pragma unroll
            for (int r = 0; r < 4; ++r)
#pragma unroll
                for (int q = 0; q < 4; ++q) patch[r][q] = base[r * 35 + q];
#pragma unroll
            for (int k = 0; k < 9; ++k) {
                int kr = k / 3, kc = k % 3;
                float4 w4 = *(const float4*)&sW[c * 144 + k * 16 + ocq * 4];  // wave-uniform
#pragma unroll
                for (int p = 0; p < 4; ++p) {
                    int dr = p >> 1, dc = p & 1;
                    float vv = patch[kr + dr][kc + dc];
                    acc[0][p] += vv * w4.x; acc[1][p] += vv * w4.y;
                    acc[2][p] += vv * w4.z; acc[3][p] += vv * w4.w;
                }
            }
        }
    }
#pragma unroll
    for (int j = 0; j < 4; ++j) {
        int oc = oc0 + ocq * 4 + j;
        float bj = bias[oc];
#pragma unroll
        for (int dr = 0; dr < 2; ++dr) {
            float2 o2 = make_float2(acc[j][dr * 2] + bj, acc[j][dr * 2 + 1] + bj);
            *(float2*)&out[((size_t)(n * 128 + oc) * 32 + r0 + 2 * prow + dr) * 32 + 2 * pcol] = o2;
        }
    }
}

// ============================================================================
// conv3: IC=128, 16x16, OC=256. Block = 1 clip x full plane x 16 oc.
// grid (16 ocg, 64 n) = 1024 blocks. Thread = 4 oc x (2x2 px). LDS stride 19.
// ============================================================================
__global__ __launch_bounds__(256) void k_conv3k(
        const float* __restrict__ in, const float* __restrict__ wt,
        const float* __restrict__ bias, float* __restrict__ out) {
    __shared__ float sIn[8 * 18 * 19];   // 2736 floats
    __shared__ float sW[8 * 144];
    int oc0 = blockIdx.x * 16, n = blockIdx.y;
    int tid = threadIdx.x;
    int ocq = tid >> 6, pxq = tid & 63;
    int prow = pxq >> 3, pcol = pxq & 7;   // px rows 2prow+dr, cols 2pcol+dc
    float acc[4][4];
#pragma unroll
    for (int j = 0; j < 4; ++j)
#pragma unroll
        for (int p = 0; p < 4; ++p) acc[j][p] = 0.f;

    for (int ic0 = 0; ic0 < 128; ic0 += 8) {
        __syncthreads();
        for (int e = tid; e < 2736; e += 256) {
            int ch = e / 342, rem = e % 342;
            int r = rem / 19, cc = rem % 19;
            int gr = r - 1, gc = cc - 1;
            float v = 0.f;
            if (gr >= 0 && gr < 16 && gc >= 0 && gc < 16)
                v = in[((size_t)(n * 128 + ic0 + ch) * 16 + gr) * 16 + gc];
            sIn[e] = v;
        }
        for (int e = tid; e < 1152; e += 256) {
            int c = e / 144, r1 = e % 144, k = r1 / 16, j = r1 % 16;
            sW[e] = wt[((size_t)(oc0 + j) * 128 + ic0 + c) * 27 + 9 + k];
        }
        __syncthreads();
        for (int c = 0; c < 8; ++c) {
            const float* base = &sIn[c * 342 + (2 * prow) * 19 + 2 * pcol];
            float patch[4][4];
#pragma unroll
            for (int r = 0; r < 4; ++r)
#pragma unroll
                for (int q = 0; q < 4; ++q) patch[r][q] = base[r * 19 + q];
#pragma unroll
            for (int k = 0; k < 9; ++k) {
                int kr = k / 3, kc = k % 3;
                float4 w4 = *(const float4*)&sW[c * 144 + k * 16 + ocq * 4];  // wave-uniform
#pragma unroll
                for (int p = 0; p < 4; ++p) {
                    int dr = p >> 1, dc = p & 1;
                    float vv = patch[kr + dr][kc + dc];
                    acc[0][p] += vv * w4.x; acc[1][p] += vv * w4.y;
                    acc[2][p] += vv * w4.z; acc[3][p] += vv * w4.w;
                }
            }
        }
    }
#pragma unroll
    for (int j = 0; j < 4; ++j) {
        int oc = oc0 + ocq * 4 + j;
        float bj = bias[oc];
#pragma unroll
        for (int dr = 0; dr < 2; ++dr) {
            float2 o2 = make_float2(acc[j][dr * 2] + bj, acc[j][dr * 2 + 1] + bj);
            *(float2*)&out[((size_t)(n * 256 + oc) * 16 + 2 * prow + dr) * 16 + 2 * pcol] = o2;
        }
    }
}

// per-(clip,channel) BN stats
__global__ void k_bn_stats(const float* __restrict__ buf, const float* __restrict__ g,
                           const float* __restrict__ be, float* __restrict__ scale,
                           float* __restrict__ shift, int C, int HW) {
    int c = blockIdx.x, ch = blockIdx.y, tid = threadIdx.x;
    float s = 0.f, s2 = 0.f;
    for (int b = 0; b < 4; ++b) {
        const float* p = buf + ((size_t)(c * 4 + b) * C + ch) * HW;
        for (int i = tid; i < HW; i += 256) { float v = p[i]; s += v; s2 += v * v; }
    }
    __shared__ float rs[256], rq[256];
    rs[tid] = s; rq[tid] = s2; __syncthreads();
    for (int k = 128; k > 0; k >>= 1) {
        if (tid < k) { rs[tid] += rs[tid + k]; rq[tid] += rq[tid + k]; }
        __syncthreads();
    }
    if (tid == 0) {
        float inv = 1.f / (float)(4 * HW);
        float m = rs[0] * inv, var = rq[0] * inv - m * m;
        float sc = g[ch] * rsqrtf(var + 1e-5f);
        scale[c * C + ch] = sc;
        shift[c * C + ch] = be[ch] - m * sc;
    }
}

__global__ void k_bn_apply_pool(const float* __restrict__ in, const float* __restrict__ scale,
                                const float* __restrict__ shift, float* __restrict__ out,
                                int C, int H, int W) {
    int OH = H >> 1, OW = W >> 1;
    size_t idx = (size_t)blockIdx.x * 256 + threadIdx.x;
    int ow = (int)(idx % OW);
    size_t r = idx / OW;
    int oh = (int)(r % OH); r /= OH;
    int ch = (int)(r % C);
    int n = (int)(r / C);
    int c = n >> 2;
    float sc = scale[c * C + ch], sh = shift[c * C + ch];
    const float* p = in + (((size_t)n * C + ch) * H + 2 * oh) * W + 2 * ow;
    float m = 0.f;
    m = fmaxf(m, p[0] * sc + sh);
    m = fmaxf(m, p[1] * sc + sh);
    m = fmaxf(m, p[W] * sc + sh);
    m = fmaxf(m, p[W + 1] * sc + sh);
    out[idx] = m;
}

// ---- post-conv3 chain ----
__global__ void k_bn_apply_avgpool4(const float* __restrict__ in, const float* __restrict__ scale,
                                    const float* __restrict__ shift, float* __restrict__ out) {
    size_t idx = (size_t)blockIdx.x * 256 + threadIdx.x;  // 262,144
    int j = (int)(idx & 3), i = (int)(idx >> 2) & 3;
    int ch = (int)(idx >> 4) & 255, n = (int)(idx >> 12);
    int c = n >> 2;
    float sc = scale[c * 256 + ch], sh = shift[c * 256 + ch];
    const float* p = in + (((size_t)n * 256 + ch) * 16 + i * 4) * 16 + j * 4;
    float s = 0.f;
#pragma unroll
    for (int r = 0; r < 4; ++r)
#pragma unroll
        for (int q = 0; q < 4; ++q) s += fmaxf(p[r * 16 + q] * sc + sh, 0.f);
    out[idx] = s * (1.f / 16.f);
}

__global__ void k_tconv(const float* __restrict__ x3p, const float* __restrict__ tw,
                        const float* __restrict__ tb, float* __restrict__ y4) {
    size_t idx = (size_t)blockIdx.x * 256 + threadIdx.x;  // 262,144
    int p = (int)(idx & 15), o = (int)(idx >> 4) & 255, n = (int)(idx >> 12);
    const float* xr = x3p + (size_t)n * 4096 + p;
    float a = tb[o];
    for (int i = 0; i < 256; ++i) a += xr[i * 16] * tw[((size_t)o * 256 + i) * 3 + 1];
    y4[idx] = a;
}

__global__ void k_bn_apply(const float* __restrict__ in, const float* __restrict__ scale,
                           const float* __restrict__ shift, float* __restrict__ out) {
    size_t idx = (size_t)blockIdx.x * 256 + threadIdx.x;  // 262,144
    int ch = (int)(idx >> 4) & 255, n = (int)(idx >> 12);
    int c = n >> 2;
    float sc = scale[c * 256 + ch], sh = shift[c * 256 + ch];
    out[idx] = fmaxf(in[idx] * sc + sh, 0.f);
}

// ============================================================================
// proj as deterministic split-K GEMM: feat[64,512] = x4[64,4096] @ pw^T + pb.
// x4 rows are clip-major (n = c*4+b); feat rows are batch-major (ro = b*16+c)
// — k_proj_fin applies the permutation.
// ============================================================================
__global__ __launch_bounds__(256) void k_proj_part(
        const float* __restrict__ A, const float* __restrict__ B, float* __restrict__ PP) {
    __shared__ __align__(16) float As[64 * 68];
    __shared__ __align__(16) float Bs[64 * 68];
    int n0 = blockIdx.x * 64, ks = blockIdx.y;
    int tid = threadIdx.x, tm = tid >> 4, tn = tid & 15;
    float acc[4][4];
#pragma unroll
    for (int i = 0; i < 4; ++i)
#pragma unroll
        for (int j = 0; j < 4; ++j) acc[i][j] = 0.f;
    int kb = ks * 512;
    for (int k0 = kb; k0 < kb + 512; k0 += 64) {
        __syncthreads();
        for (int e = tid; e < 4096; e += 256) {
            int m = e >> 6, k = e & 63;
            As[k * 68 + m] = A[(size_t)m * 4096 + k0 + k];
            Bs[k * 68 + m] = B[(size_t)(n0 + m) * 4096 + k0 + k];
        }
        __syncthreads();
        for (int k = 0; k < 64; ++k) {
            float4 a4 = *(const float4*)&As[k * 68 + tm * 4];
            float4 b4 = *(const float4*)&Bs[k * 68 + tn * 4];
            acc[0][0] += a4.x * b4.x; acc[0][1] += a4.x * b4.y;
            acc[0][2] += a4.x * b4.z; acc[0][3] += a4.x * b4.w;
            acc[1][0] += a4.y * b4.x; acc[1][1] += a4.y * b4.y;
            acc[1][2] += a4.y * b4.z; acc[1][3] += a4.y * b4.w;
            acc[2][0] += a4.z * b4.x; acc[2][1] += a4.z * b4.y;
            acc[2][2] += a4.z * b4.z; acc[2][3] += a4.z * b4.w;
            acc[3][0] += a4.w * b4.x; acc[3][1] += a4.w * b4.y;
            acc[3][2] += a4.w * b4.z; acc[3][3] += a4.w * b4.w;
        }
    }
#pragma unroll
    for (int i = 0; i < 4; ++i)
#pragma unroll
        for (int j = 0; j < 4; ++j)
            PP[((size_t)(ks * 64 + tm * 4 + i)) * 512 + n0 + tn * 4 + j] = acc[i][j];
}

__global__ void k_proj_fin(const float* __restrict__ PP, const float* __restrict__ pb,
                           float* __restrict__ feat) {
    int e = blockIdx.x * 256 + threadIdx.x;  // 32768
    int n = e & 511;
    int m = e >> 9;               // x4 row (clip-major): m = c*4 + b
    float s = pb[n];
#pragma unroll
    for (int ks = 0; ks < 8; ++ks) s += PP[(size_t)ks * 32768 + e];
    int c = m >> 2, b = m & 3;
    int ro = b * 16 + c;          // feat row (batch-major)
    feat[(size_t)ro * 512 + n] = s;
}

// VQ argmin; min distance -> commitArr[row] (deterministic)
__global__ void k_vq(const float* __restrict__ feat, const float* __restrict__ cb,
                     float* __restrict__ quant, float* __restrict__ commitArr) {
    int row = blockIdx.x, tid = threadIdx.x;
    __shared__ float f[512];
    for (int k = tid; k < 512; k += 256) f[k] = feat[(size_t)row * 512 + k];
    __syncthreads();
    float best = 3.4e38f; int bidx = 0;
    for (int j = tid; j < 1024; j += 256) {
        const float* c = cb + (size_t)j * 512;
        float d2 = 0.f;
        for (int k = 0; k < 512; ++k) { float t = f[k] - c[k]; d2 += t * t; }
        if (d2 < best) { best = d2; bidx = j; }
    }
    __shared__ float rd[256]; __shared__ int ri[256];
    rd[tid] = best; ri[tid] = bidx; __syncthreads();
    for (int k = 128; k > 0; k >>= 1) {
        if (tid < k) {
            float od = rd[tid + k]; int oi = ri[tid + k];
            if (od < rd[tid] || (od == rd[tid] && oi < ri[tid])) { rd[tid] = od; ri[tid] = oi; }
        }
        __syncthreads();
    }
    __shared__ int wsel;
    if (tid == 0) { wsel = ri[0]; commitArr[row] = rd[0]; }
    __syncthreads();
    const float* c = cb + (size_t)wsel * 512;
    for (int k = tid; k < 512; k += 256) quant[(size_t)row * 512 + k] = c[k];
}

// gi = X @ w_ih.T + b_ih, rows (b, t) t=0..14; X and gi rows at stride-16 (b*16+t)
__global__ void k_gru_gi(const float* __restrict__ x, const float* __restrict__ wih,
                         const float* __restrict__ bih, float* __restrict__ gi) {
    int r = blockIdx.x;  // 0..59
    int b = r / 15, t = r % 15;
    const float* xr = x + ((size_t)(b * 16 + t)) * 512;
    __shared__ float xsRow[512];
    for (int k = threadIdx.x; k < 512; k += 256) xsRow[k] = xr[k];
    __syncthreads();
    const float4* xp = (const float4*)xsRow;
    for (int d = threadIdx.x; d < 1536; d += 256) {
        const float4* wr = (const float4*)(wih + (size_t)d * 512);
        float a0 = 0.f, a1 = 0.f, a2 = 0.f, a3 = 0.f;
        for (int i = 0; i < 128; i += 4) {
            float4 w0 = wr[i], w1 = wr[i + 1], w2 = wr[i + 2], w3 = wr[i + 3];
            float4 x0 = xp[i], x1 = xp[i + 1], x2 = xp[i + 2], x3 = xp[i + 3];
            a0 += w0.x * x0.x + w0.y * x0.y + w0.z * x0.z + w0.w * x0.w;
            a1 += w1.x * x1.x + w1.y * x1.y + w1.z * x1.z + w1.w * x1.w;
            a2 += w2.x * x2.x + w2.y * x2.y + w2.z * x2.z + w2.w * x2.w;
            a3 += w3.x * x3.x + w3.y * x3.y + w3.z * x3.z + w3.w * x3.w;
        }
        gi[((size_t)(b * 16 + t)) * 1536 + d] = (a0 + a1) + (a2 + a3) + bih[d];
    }
}

// One GRU step: grid 128 (4 h-dims each), wave = one h-dim, float4 rows.
__global__ void k_gru_step2(const float* __restrict__ gi, const float* __restrict__ whh,
                            const float* __restrict__ bhh, float* __restrict__ hseq, int t) {
    int wv = threadIdx.x >> 6, lane = threadIdx.x & 63;
    int d = blockIdx.x * 4 + wv;
    const float4* w0p = (const float4*)(whh + (size_t)d * 512);
    const float4* w1p = (const float4*)(whh + (size_t)(512 + d) * 512);
    const float4* w2p = (const float4*)(whh + (size_t)(1024 + d) * 512);
    float4 w0a = w0p[lane * 2], w0b = w0p[lane * 2 + 1];
    float4 w1a = w1p[lane * 2], w1b = w1p[lane * 2 + 1];
    float4 w2a = w2p[lane * 2], w2b = w2p[lane * 2 + 1];
    float bh0 = bhh[d], bh1 = bhh[512 + d], bh2 = bhh[1024 + d];
    for (int b = 0; b < 4; ++b) {
        float4 ha = make_float4(0, 0, 0, 0), hb = ha;
        float hpd = 0.f;
        if (t > 0) {
            const float4* hp = (const float4*)(hseq + (size_t)(b * 16 + t - 1) * 512);
            ha = hp[lane * 2]; hb = hp[lane * 2 + 1];
            hpd = hseq[(size_t)(b * 16 + t - 1) * 512 + d];
        }
        float s0 = w0a.x * ha.x + w0a.y * ha.y + w0a.z * ha.z + w0a.w * ha.w
                 + w0b.x * hb.x + w0b.y * hb.y + w0b.z * hb.z + w0b.w * hb.w;
        float s1 = w1a.x * ha.x + w1a.y * ha.y + w1a.z * ha.z + w1a.w * ha.w
                 + w1b.x * hb.x + w1b.y * hb.y + w1b.z * hb.z + w1b.w * hb.w;
        float s2 = w2a.x * ha.x + w2a.y * ha.y + w2a.z * ha.z + w2a.w * ha.w
                 + w2b.x * hb.x + w2b.y * hb.y + w2b.z * hb.z + w2b.w * hb.w;
#pragma unroll
        for (int m = 1; m < 64; m <<= 1) {
            s0 += __shfl_xor(s0, m);
            s1 += __shfl_xor(s1, m);
            s2 += __shfl_xor(s2, m);
        }
        const float* gr = gi + (size_t)(b * 16 + t) * 1536;
        float rr = 1.f / (1.f + expf(-(gr[d] + s0 + bh0)));
        float zz = 1.f / (1.f + expf(-(gr[512 + d] + s1 + bh1)));
        float nn = tanhf(gr[1024 + d] + rr * (s2 + bh2));
        if (lane == 0)
            hseq[(size_t)(b * 16 + t) * 512 + d] = (1.f - zz) * nn + zz * hpd;
    }
}

// ctx loss partials -> ctxArr[block] (deterministic)
__global__ void k_ctx_loss(const float* __restrict__ h2, const float* __restrict__ feat,
                           float* __restrict__ ctxArr) {
    int tid = threadIdx.x;
    size_t idx = (size_t)blockIdx.x * 256 + tid;  // 30720
    int d = (int)(idx & 511);
    int rt = (int)(idx >> 9);
    int t = rt % 15, b = rt / 15;
    float diff = h2[(size_t)(b * 16 + t) * 512 + d] - feat[(size_t)(b * 16 + t + 1) * 512 + d];
    float v = diff * diff;
#pragma unroll
    for (int m = 1; m < 64; m <<= 1) v += __shfl_xor(v, m);
    __shared__ float ws[4];
    if ((tid & 63) == 0) ws[tid >> 6] = v;
    __syncthreads();
    if (tid == 0) ctxArr[blockIdx.x] = ((ws[0] + ws[1]) + (ws[2] + ws[3]));
}

__global__ void k_word_vq(const float* __restrict__ quant, const float* __restrict__ wcb,
                          float* __restrict__ wemb, float* __restrict__ out_widx) {
    int row = blockIdx.x;  // b*8+wi
    int b = row >> 3, wi = row & 7;
    int tid = threadIdx.x;
    __shared__ float f[512];
    for (int k = tid; k < 512; k += 256)
        f[k] = 0.5f * (quant[(size_t)(b * 16 + 2 * wi) * 512 + k] +
                       quant[(size_t)(b * 16 + 2 * wi + 1) * 512 + k]);
    __syncthreads();
    const float* cp = wcb + (size_t)tid * 512;
    float d2 = 0.f;
    for (int k = 0; k < 512; ++k) { float t = f[k] - cp[k]; d2 += t * t; }
    __shared__ float rd[256]; __shared__ int ri[256];
    rd[tid] = d2; ri[tid] = tid; __syncthreads();
    for (int k = 128; k > 0; k >>= 1) {
        if (tid < k) {
            float od = rd[tid + k]; int oi = ri[tid + k];
            if (od < rd[tid] || (od == rd[tid] && oi < ri[tid])) { rd[tid] = od; ri[tid] = oi; }
        }
        __syncthreads();
    }
    __shared__ int wsel;
    if (tid == 0) { wsel = ri[0]; out_widx[row] = (float)ri[0]; }
    __syncthreads();
    const float* cb = wcb + (size_t)wsel * 512;
    for (int k = tid; k < 512; k += 256) wemb[(size_t)row * 512 + k] = cb[k];
}

// alignment partials -> alignArr[row] (deterministic)
__global__ void k_align(const float* __restrict__ wemb, const float* __restrict__ aw,
                        const float* __restrict__ ab, float* __restrict__ alignArr) {
    int row = blockIdx.x, tid = threadIdx.x;
    __shared__ float e[512];
    for (int k = tid; k < 512; k += 256) e[k] = wemb[(size_t)row * 512 + k];
    __syncthreads();
    float local = 0.f;
    for (int d = tid; d < 512; d += 256) {
        const float* wr = aw + (size_t)d * 512;
        float a = ab[d] - e[d];
        for (int k = 0; k < 512; ++k) a += e[k] * wr[k];
        local += a * a;
    }
    __shared__ float rs[256];
    rs[tid] = local; __syncthreads();
    for (int k = 128; k > 0; k >>= 1) { if (tid < k) rs[tid] += rs[tid + k]; __syncthreads(); }
    if (tid == 0) alignArr[row] = rs[0];
}

__global__ void k_ctx(const float* __restrict__ wemb, float* __restrict__ ctx) {
    int e = blockIdx.x * 256 + threadIdx.x;  // 2048
    int b = e >> 9, d = e & 511;
    float s = 0.f;
#pragma unroll
    for (int wi = 0; wi < 8; ++wi) s += wemb[(size_t)(b * 8 + wi) * 512 + d];
    ctx[e] = s * 0.125f;
}

// small-M (M=4) GEMV: C[4,N] = A[4,K] @ B[N,K]^T + bias, optional relu.
__global__ void k_smallM(const float* __restrict__ A, const float* __restrict__ B,
                         const float* __restrict__ bias, float* __restrict__ C,
                         int N, int K, int relu) {
    __shared__ float xs[4096];
    int tid = threadIdx.x;
    for (int e = tid; e < 4 * K; e += 256) xs[e] = A[e];
    __syncthreads();
    int r = tid >> 4, kt = tid & 15;
    int n = blockIdx.x * 16 + r;
    float acc[4] = {0, 0, 0, 0};
    if (n < N) {
        int iters = K >> 6;
        for (int i = 0; i < iters; ++i) {
            int k = i * 64 + kt * 4;
            float4 w = *(const float4*)&B[(size_t)n * K + k];
#pragma unroll
            for (int b = 0; b < 4; ++b) {
                float4 x = *(const float4*)&xs[b * K + k];
                acc[b] += w.x * x.x + w.y * x.y + w.z * x.z + w.w * x.w;
            }
        }
    }
#pragma unroll
    for (int b = 0; b < 4; ++b) {
#pragma unroll
        for (int m = 1; m < 16; m <<= 1) acc[b] += __shfl_xor(acc[b], m);
    }
    if (kt == 0 && n < N) {
#pragma unroll
        for (int b = 0; b < 4; ++b) {
            float v = acc[b] + bias[n];
            if (relu) v = fmaxf(v, 0.f);
            C[(size_t)b * N + n] = v;
        }
    }
}

// log-softmax CE + deterministic fixed-order sum of all loss partials
__global__ void k_final(const float* __restrict__ logits, const int* __restrict__ tokens,
                        const float* __restrict__ commitArr, const float* __restrict__ ctxArr,
                        const float* __restrict__ alignArr, float* __restrict__ out_total) {
    int tid = threadIdx.x;
    __shared__ float rs[256];
    __shared__ float sM;
    float tr = 0.f;
    for (int b = 0; b < 4; ++b) {
        const float* lg = logits + (size_t)b * 3000;
        float m = -1e30f;
        for (int d = tid; d < 3000; d += 256) m = fmaxf(m, lg[d]);
        rs[tid] = m; __syncthreads();
        for (int k = 128; k > 0; k >>= 1) { if (tid < k) rs[tid] = fmaxf(rs[tid], rs[tid + k]); __syncthreads(); }
        if (tid == 0) sM = rs[0];
        __syncthreads();
        float M = sM;
        float s = 0.f;
        for (int d = tid; d < 3000; d += 256) s += expf(lg[d] - M);
        rs[tid] = s; __syncthreads();
        for (int k = 128; k > 0; k >>= 1) { if (tid < k) rs[tid] += rs[tid + k]; __syncthreads(); }
        if (tid == 0) {
            int t0 = tokens[b * 10];
            tr += -(lg[t0] - M - logf(rs[0]));
        }
        __syncthreads();
    }
    if (tid == 0) {
        float c0 = 0.f;
        for (int i = 0; i < 64; ++i) c0 += commitArr[i];
        float c1 = 0.f;
        for (int i = 0; i < 120; ++i) c1 += ctxArr[i];
        float c2 = 0.f;
        for (int i = 0; i < 32; ++i) c2 += alignArr[i];
        float total = 1.25f * c0 * (1.f / 32768.f)
                    + 0.1f  * c1 * (1.f / 30720.f)
                    + 0.1f  * c2 * (1.f / 16384.f)
                    + tr;
        *out_total = total;
    }
}

extern "C" void kernel_launch(void* const* d_in, const int* in_sizes, int n_in,
                              void* d_out, int out_size, void* d_ws, size_t ws_size,
                              hipStream_t stream) {
    (void)in_sizes; (void)n_in; (void)out_size; (void)ws_size;
    const float* videos   = (const float*)d_in[0];
    const float* conv1_w  = (const float*)d_in[1];
    const float* conv1_b  = (const float*)d_in[2];
    const float* bn1_g    = (const float*)d_in[3];
    const float* bn1_b    = (const float*)d_in[4];
    const float* conv2_w  = (const float*)d_in[5];
    const float* conv2_b  = (const float*)d_in[6];
    const float* bn2_g    = (const float*)d_in[7];
    const float* bn2_b    = (const float*)d_in[8];
    const float* conv3_w  = (const float*)d_in[9];
    const float* conv3_b  = (const float*)d_in[10];
    const float* bn3_g    = (const float*)d_in[11];
    const float* bn3_b    = (const float*)d_in[12];
    const float* tconv_w  = (const float*)d_in[13];
    const float* tconv_b  = (const float*)d_in[14];
    const float* bn4_g    = (const float*)d_in[15];
    const float* bn4_b    = (const float*)d_in[16];
    const float* proj_w   = (const float*)d_in[17];
    const float* proj_b   = (const float*)d_in[18];
    const float* codebook = (const float*)d_in[19];
    const float* word_cb  = (const float*)d_in[20];
    const float* align_w  = (const float*)d_in[21];
    const float* align_b  = (const float*)d_in[22];
    const float* gru_wih0 = (const float*)d_in[23];
    const float* gru_whh0 = (const float*)d_in[24];
    const float* gru_bih0 = (const float*)d_in[25];
    const float* gru_bhh0 = (const float*)d_in[26];
    const float* gru_wih1 = (const float*)d_in[27];
    const float* gru_whh1 = (const float*)d_in[28];
    const float* gru_bih1 = (const float*)d_in[29];
    const float* gru_bhh1 = (const float*)d_in[30];
    const float* dec1_w   = (const float*)d_in[31];
    const float* dec1_b   = (const float*)d_in[32];
    const float* dec2_w   = (const float*)d_in[33];
    const float* dec2_b   = (const float*)d_in[34];
    const float* dec3_w   = (const float*)d_in[35];
    const float* dec3_b   = (const float*)d_in[36];
    const int*   tokens   = (const int*)d_in[37];

    float* wsf    = (float*)d_ws;
    float* out    = (float*)d_out;
    float* x1p    = wsf + OFF_X1P;
    float* x2p    = wsf + OFF_X2P;
    float* y2     = wsf + OFF_Y2;
    float* y3     = wsf + OFF_Y3;
    float* x3p    = wsf + OFF_X3P;
    float* y4     = wsf + OFF_Y4;
    float* x4     = wsf + OFF_X4;
    float* feat   = wsf + OFF_FEAT;
    float* quant  = wsf + OFF_QUANT;
    float* gi1    = wsf + OFF_GI1;
    float* gi2    = wsf + OFF_GI2;
    float* h1     = wsf + OFF_H1;
    float* h2     = wsf + OFF_H2;
    float* wemb   = wsf + OFF_WEMB;
    float* ctx    = wsf + OFF_CTX;
    float* hh1    = wsf + OFF_HH1;
    float* hh2    = wsf + OFF_HH2;
    float* logit  = wsf + OFF_LOG;
    float* pp     = wsf + OFF_PP;
    float* sc     = wsf + OFF_SC;
    float* sh     = wsf + OFF_SH;
    float* accP   = wsf + OFF_ACCP;
    float* commitA= wsf + OFF_COMMIT;
    float* ctxA   = wsf + OFF_CTXA;
    float* alignA = wsf + OFF_ALIGNA;

    // conv1 + bn1 + pool
    k_conv1_stats2<<<dim3(4, 64), 256, 0, stream>>>(videos, conv1_w, conv1_b, accP);
    k_conv1_fin<<<4, 256, 0, stream>>>(accP, bn1_g, bn1_b, sc, sh);
    k_conv1_apply2<<<dim3(4, 64), 256, 0, stream>>>(videos, conv1_w, conv1_b, sc, sh, x1p);
    // conv2 + bn2 + pool
    k_conv2<<<dim3(8, 4, 64), 256, 0, stream>>>(x1p, conv2_w, conv2_b, y2);
    k_bn_stats<<<dim3(16, 128), 256, 0, stream>>>(y2, bn2_g, bn2_b, sc, sh, 128, 1024);
    k_bn_apply_pool<<<8192, 256, 0, stream>>>(y2, sc, sh, x2p, 128, 32, 32);
    // conv3 + bn3 + chain
    k_conv3k<<<dim3(16, 64), 256, 0, stream>>>(x2p, conv3_w, conv3_b, y3);
    k_bn_stats<<<dim3(16, 256), 256, 0, stream>>>(y3, bn3_g, bn3_b, sc, sh, 256, 256);
    k_bn_apply_avgpool4<<<1024, 256, 0, stream>>>(y3, sc, sh, x3p);
    k_tconv<<<1024, 256, 0, stream>>>(x3p, tconv_w, tconv_b, y4);
    k_bn_stats<<<dim3(16, 256), 256, 0, stream>>>(y4, bn4_g, bn4_b, sc, sh, 256, 16);
    k_bn_apply<<<1024, 256, 0, stream>>>(y4, sc, sh, x4);
    // projection (deterministic split-K GEMM, with row permutation in fin)
    k_proj_part<<<dim3(8, 8), 256, 0, stream>>>(x4, proj_w, pp);
    k_proj_fin<<<128, 256, 0, stream>>>(pp, proj_b, feat);
    k_vq<<<64, 256, 0, stream>>>(feat, codebook, quant, commitA);
    // GRU layer 1
    k_gru_gi<<<60, 256, 0, stream>>>(quant, gru_wih0, gru_bih0, gi1);
    for (int t = 0; t < 15; ++t)
        k_gru_step2<<<128, 256, 0, stream>>>(gi1, gru_whh0, gru_bhh0, h1, t);
    // GRU layer 2
    k_gru_gi<<<60, 256, 0, stream>>>(h1, gru_wih1, gru_bih1, gi2);
    for (int t = 0; t < 15; ++t)
        k_gru_step2<<<128, 256, 0, stream>>>(gi2, gru_whh1, gru_bhh1, h2, t);
    k_ctx_loss<<<120, 256, 0, stream>>>(h2, feat, ctxA);
    // word VQ + alignment
    k_word_vq<<<32, 256, 0, stream>>>(quant, word_cb, wemb, out);
    k_align<<<32, 256, 0, stream>>>(wemb, align_w, align_b, alignA);
    // decoder
    k_ctx<<<8, 256, 0, stream>>>(wemb, ctx);
    k_smallM<<<32, 256, 0, stream>>>(ctx, dec1_w, dec1_b, hh1, 512, 512, 1);
    k_smallM<<<64, 256, 0, stream>>>(hh1, dec2_w, dec2_b, hh2, 1024, 512, 1);
    k_smallM<<<188, 256, 0, stream>>>(hh2, dec3_w, dec3_b, logit, 3000, 1024, 0);
    k_final<<<1, 256, 0, stream>>>(logit, tokens, commitA, ctxA, alignA, out + 32);
}